// Round 1
// baseline (3762.978 us; speedup 1.0000x reference)
//
#include <hip/hip_runtime.h>

namespace {

constexpr int B_TOT  = 2048;
constexpr int T_SEQ  = 66;
constexpr int IN_DIM = 9;
constexpr int H      = 100;
constexpr int N      = 128;
constexpr int D      = 20;
constexpr int MP     = 21;   // padded M row stride (bank-conflict-free)
constexpr int OUTD   = 8;
constexpr int NHEADS = 2;
constexpr int PPH    = D + 1 + 1 + 3 + 1;        // 26
constexpr int PDIM   = NHEADS * PPH + 2 * D;     // 92
constexpr float CLIPV = 20.0f;
constexpr int G      = 8;     // sequences per block
constexpr int NTHR   = 1024;
constexpr int CTRL   = IN_DIM + D;  // 29
constexpr int G4     = 4 * H;       // 400

// LDS layout (floats)
constexpr int OFF_M     = 0;
constexpr int OFF_H     = OFF_M + G * N * MP;        // [G][H]
constexpr int OFF_C     = OFF_H + G * H;
constexpr int OFF_R     = OFF_C + G * H;             // [G][D]
constexpr int OFF_CTRL  = OFF_R + G * D;             // [G][32]
constexpr int OFF_GATES = OFF_CTRL + G * 32;         // [G][400]
constexpr int OFF_P     = OFF_GATES + G * G4;        // [G][96]
constexpr int OFF_KV    = OFF_P + G * 96;            // [G*2][D]
constexpr int OFF_SCAL  = OFF_KV + G * 2 * D;        // [G*2][8]
constexpr int OFF_EA    = OFF_SCAL + G * 2 * 8;      // [G*2][D]
constexpr int OFF_MN    = OFF_EA + G * 2 * D;        // [G][N]
constexpr int OFF_WG    = OFF_MN + G * N;            // [G*2][N]
constexpr int OFF_W     = OFF_WG + G * 2 * N;        // [G*2][N]
constexpr int OFF_RN    = OFF_W + G * 2 * N;         // [G][D]
constexpr int OFF_HO    = OFF_RN + G * D;            // [G][OUTD]
constexpr int SMEM_FLOATS = OFF_HO + G * OUTD;
constexpr int SMEM_BYTES  = SMEM_FLOATS * 4;

__device__ __forceinline__ float fexp2(float x) { return __builtin_amdgcn_exp2f(x); }
__device__ __forceinline__ float flog2(float x) { return __builtin_amdgcn_logf(x); }
__device__ __forceinline__ float frcp(float x)  { return __builtin_amdgcn_rcpf(x); }
__device__ __forceinline__ float fexp(float x)  { return fexp2(x * 1.4426950408889634f); }
__device__ __forceinline__ float fsig(float x)  { return frcp(1.f + fexp2(-1.4426950408889634f * x)); }
__device__ __forceinline__ float ftanh(float x) { return 1.f - 2.f * frcp(1.f + fexp2(2.8853900817779268f * x)); }
__device__ __forceinline__ float fsoftplus(float x) { return log1pf(fexp(x)); }

__device__ __forceinline__ float wred_max(float v) {
#pragma unroll
  for (int off = 32; off; off >>= 1) v = fmaxf(v, __shfl_xor(v, off, 64));
  return v;
}
__device__ __forceinline__ float wred_sum(float v) {
#pragma unroll
  for (int off = 32; off; off >>= 1) v += __shfl_xor(v, off, 64);
  return v;
}

__global__ __launch_bounds__(NTHR, 1) void ntm_kernel(
    const float* __restrict__ inputs, const float* __restrict__ Wx,
    const float* __restrict__ Wh, const float* __restrict__ b_lstm,
    const float* __restrict__ W_params, const float* __restrict__ b_params,
    const float* __restrict__ W_out, const float* __restrict__ b_out,
    const int* __restrict__ seqp, float* __restrict__ out) {
  extern __shared__ float sm[];
  float* sM    = sm + OFF_M;
  float* sh    = sm + OFF_H;
  float* sc    = sm + OFF_C;
  float* sr    = sm + OFF_R;
  float* sctrl = sm + OFF_CTRL;
  float* sgates= sm + OFF_GATES;
  float* sp    = sm + OFF_P;
  float* skv   = sm + OFF_KV;
  float* sscal = sm + OFF_SCAL;
  float* sea   = sm + OFF_EA;
  float* sMn   = sm + OFF_MN;
  float* swg   = sm + OFF_WG;
  float* sw    = sm + OFF_W;
  float* srn   = sm + OFF_RN;
  float* sho   = sm + OFF_HO;

  const int tid = threadIdx.x;
  const int b0  = blockIdx.x * G;
  const int seq  = seqp[0];
  const int tlim = seq + 1;
  const int TO   = T_SEQ - tlim;

  // ---- init state ----
  for (int i = tid; i < G * N * MP; i += NTHR) sM[i] = 1e-6f;
  for (int i = tid; i < G * H; i += NTHR) { sh[i] = 0.f; sc[i] = 0.f; }
  for (int i = tid; i < G * D; i += NTHR) sr[i] = 0.f;
  for (int i = tid; i < G * 2 * N; i += NTHR) sw[i] = ((i & (N - 1)) == 0) ? 1.f : 0.f;
  if (tid < G * 32) {
    int g = tid >> 5, k = tid & 31;
    float v = 0.f;
    if (k < IN_DIM) v = inputs[(size_t)(b0 + g) * T_SEQ * IN_DIM + k];
    sctrl[tid] = v;
  }
  __syncthreads();

  for (int t = 0; t < T_SEQ; ++t) {
    // ---- phase 1: gates = ctrl@Wx + h@Wh + b ----
    if (tid < 800) {
      int g = tid / 100, jq = tid - g * 100;
      float4 acc = *(const float4*)(b_lstm + jq * 4);
      const float* ct = sctrl + g * 32;
      for (int k = 0; k < CTRL; ++k) {
        float4 wv = *(const float4*)(Wx + k * G4 + jq * 4);
        float cv = ct[k];
        acc.x = fmaf(cv, wv.x, acc.x); acc.y = fmaf(cv, wv.y, acc.y);
        acc.z = fmaf(cv, wv.z, acc.z); acc.w = fmaf(cv, wv.w, acc.w);
      }
      const float* hh = sh + g * H;
      for (int k = 0; k < H; ++k) {
        float4 wv = *(const float4*)(Wh + k * G4 + jq * 4);
        float hv = hh[k];
        acc.x = fmaf(hv, wv.x, acc.x); acc.y = fmaf(hv, wv.y, acc.y);
        acc.z = fmaf(hv, wv.z, acc.z); acc.w = fmaf(hv, wv.w, acc.w);
      }
      *(float4*)(sgates + g * G4 + jq * 4) = acc;
    }
    __syncthreads();

    // ---- phase 2: LSTM pointwise ----
    if (tid < 800) {
      int g = tid / 100, e = tid - g * 100;
      const float* gt = sgates + g * G4;
      float gi = gt[e], gf = gt[H + e], gz = gt[2 * H + e], go = gt[3 * H + e];
      float cc = fsig(gf) * sc[g * H + e] + fsig(gi) * ftanh(gz);
      float hv = fsig(go) * ftanh(cc);
      sc[g * H + e] = cc;
      sh[g * H + e] = hv;
    }
    __syncthreads();

    // ---- phase 3: p = clip(h@W_params + b) ; Mn = ||M_n|| ----
    if (tid < G * 23) {
      int g = tid / 23, jq = tid - g * 23;
      float4 acc = *(const float4*)(b_params + jq * 4);
      const float* hh = sh + g * H;
      for (int k = 0; k < H; ++k) {
        float4 wv = *(const float4*)(W_params + k * PDIM + jq * 4);
        float hv = hh[k];
        acc.x = fmaf(hv, wv.x, acc.x); acc.y = fmaf(hv, wv.y, acc.y);
        acc.z = fmaf(hv, wv.z, acc.z); acc.w = fmaf(hv, wv.w, acc.w);
      }
      acc.x = fminf(fmaxf(acc.x, -CLIPV), CLIPV);
      acc.y = fminf(fmaxf(acc.y, -CLIPV), CLIPV);
      acc.z = fminf(fmaxf(acc.z, -CLIPV), CLIPV);
      acc.w = fminf(fmaxf(acc.w, -CLIPV), CLIPV);
      *(float4*)(sp + g * 96 + jq * 4) = acc;
    }
    {
      int g = tid >> 7, n = tid & (N - 1);
      const float* Mr = sM + (g * N + n) * MP;
      float s = 0.f;
#pragma unroll
      for (int d = 0; d < D; ++d) s = fmaf(Mr[d], Mr[d], s);
      sMn[g * N + n] = sqrtf(s);
    }
    __syncthreads();

    // ---- phase 4: per-head scalars, key vec, erase/add vecs ----
    if (tid < G * NHEADS) {
      int gh = tid;
      int g = gh >> 1, hd = gh & 1;
      const float* pp = sp + g * 96 + hd * PPH;
      float ss = 0.f;
#pragma unroll
      for (int d = 0; d < D; ++d) {
        float kv = ftanh(pp[d]);
        skv[gh * D + d] = kv;
        ss = fmaf(kv, kv, ss);
      }
      float kn    = sqrtf(ss);
      float beta  = fsoftplus(pp[D]);
      float gg    = fsig(pp[D + 1]);
      float a0 = pp[D + 2], a1 = pp[D + 3], a2 = pp[D + 4];
      float mx = fmaxf(a0, fmaxf(a1, a2));
      float e0 = fexp(a0 - mx), e1 = fexp(a1 - mx), e2 = fexp(a2 - mx);
      float inv = frcp(e0 + e1 + e2);
      float gamma = fsoftplus(pp[D + 5]) + 1.f;
      float* scp = sscal + gh * 8;
      scp[0] = beta; scp[1] = gg; scp[2] = e0 * inv; scp[3] = e1 * inv;
      scp[4] = e2 * inv; scp[5] = gamma; scp[6] = kn;
    }
    if (tid >= 64 && tid < 64 + G * 2 * D) {
      int q = tid - 64;
      int g = q / (2 * D), j = q - g * (2 * D);
      float v = sp[g * 96 + NHEADS * PPH + j];
      int isA = (j >= D);
      sea[(g * 2 + isA) * D + (isA ? j - D : j)] = isA ? ftanh(v) : fsig(v);
    }
    __syncthreads();

    // ---- phase 5: addressing (one wave per (g,head)) ----
    {
      int gh = tid >> 6, l = tid & 63;
      int g = gh >> 1;
      const float* kv  = skv + gh * D;
      const float* scp = sscal + gh * 8;
      float beta = scp[0], gg = scp[1], s0 = scp[2], s1 = scp[3], s2 = scp[4];
      float gamma = scp[5], kn = scp[6];
      int n0 = l, n1 = l + 64;
      const float* M0 = sM + (g * N + n0) * MP;
      const float* M1 = sM + (g * N + n1) * MP;
      float d0 = 0.f, d1 = 0.f;
#pragma unroll
      for (int d = 0; d < D; ++d) {
        float kd = kv[d];
        d0 = fmaf(kd, M0[d], d0);
        d1 = fmaf(kd, M1[d], d1);
      }
      float S0 = beta * d0 * frcp(kn * sMn[g * N + n0] + 1e-8f);
      float S1 = beta * d1 * frcp(kn * sMn[g * N + n1] + 1e-8f);
      float m = wred_max(fmaxf(S0, S1));
      float e0 = fexp(S0 - m), e1 = fexp(S1 - m);
      float sinv = frcp(wred_sum(e0 + e1));
      float wc0 = e0 * sinv, wc1 = e1 * sinv;
      float wp0 = sw[gh * N + n0], wp1 = sw[gh * N + n1];
      float wg0 = fmaf(gg, wc0 - wp0, wp0);
      float wg1 = fmaf(gg, wc1 - wp1, wp1);
      swg[gh * N + n0] = wg0;
      swg[gh * N + n1] = wg1;
      __syncthreads();
      float wtp0 = swg[gh * N + ((n0 + 1) & (N - 1))];
      float wtm0 = swg[gh * N + ((n0 + N - 1) & (N - 1))];
      float wtp1 = swg[gh * N + ((n1 + 1) & (N - 1))];
      float wtm1 = swg[gh * N + ((n1 + N - 1) & (N - 1))];
      float wt0 = s0 * wtp0 + s1 * wg0 + s2 * wtm0;
      float wt1 = s0 * wtp1 + s1 * wg1 + s2 * wtm1;
      wt0 = fmaxf(wt0, 1e-16f);
      wt1 = fmaxf(wt1, 1e-16f);
      float invm = frcp(wred_max(fmaxf(wt0, wt1)));
      float p0 = fexp2(gamma * flog2(wt0 * invm));
      float p1 = fexp2(gamma * flog2(wt1 * invm));
      float pinv = frcp(wred_sum(p0 + p1));
      sw[gh * N + n0] = p0 * pinv;
      sw[gh * N + n1] = p1 * pinv;
    }
    __syncthreads();

    // ---- phase 6: r_new = w_r @ M ; hout = h @ W_out[:H] ----
    if (tid < G * D) {
      int g = tid / D, d = tid - g * D;
      const float* wr = sw + (g * 2) * N;
      float s = 0.f;
      for (int n = 0; n < N; ++n) s = fmaf(wr[n], sM[(g * N + n) * MP + d], s);
      srn[g * D + d] = s;
      sr[g * D + d] = s;
    } else if (tid >= 256 && tid < 256 + G * OUTD) {
      int q = tid - 256;
      int g = q >> 3, o = q & 7;
      const float* hh = sh + g * H;
      float s = 0.f;
      for (int k = 0; k < H; ++k) s = fmaf(hh[k], W_out[k * OUTD + o], s);
      sho[g * OUTD + o] = s;
    }
    __syncthreads();

    // ---- phase 7: M update ; output ; next ctrl ----
    {
      int g = tid >> 7, n = tid & (N - 1);
      float ww = sw[(g * 2 + 1) * N + n];
      float* Mr = sM + (g * N + n) * MP;
      const float* ep = sea + (g * 2) * D;
      const float* ap = sea + (g * 2 + 1) * D;
#pragma unroll
      for (int d = 0; d < D; ++d) {
        float mv = Mr[d];
        Mr[d] = fmaf(ww, fmaf(-ep[d], mv, ap[d]), mv);  // m*(1-ww*e)+ww*a
      }
    }
    if (t >= tlim && tid < G * OUTD) {
      int g = tid >> 3, o = tid & 7;
      float s = sho[g * OUTD + o] + b_out[o];
      const float* rn = srn + g * D;
#pragma unroll
      for (int d = 0; d < D; ++d) s = fmaf(rn[d], W_out[(H + d) * OUTD + o], s);
      s = fminf(fmaxf(s, -CLIPV), CLIPV);
      out[((size_t)(b0 + g) * TO + (t - tlim)) * OUTD + o] = fsig(s);
    }
    if (t + 1 < T_SEQ && tid >= 512 && tid < 512 + G * 32) {
      int q = tid - 512;
      int g = q >> 5, k = q & 31;
      float v = 0.f;
      if (k < IN_DIM) v = inputs[((size_t)(b0 + g) * T_SEQ + (t + 1)) * IN_DIM + k];
      else if (k < CTRL) v = sr[g * D + (k - IN_DIM)];
      sctrl[q] = v;
    }
    __syncthreads();
  }
}

}  // namespace

extern "C" void kernel_launch(void* const* d_in, const int* in_sizes, int n_in,
                              void* d_out, int out_size, void* d_ws, size_t ws_size,
                              hipStream_t stream) {
  (void)in_sizes; (void)n_in; (void)d_ws; (void)ws_size; (void)out_size;
  const float* inputs   = (const float*)d_in[0];
  const float* Wx       = (const float*)d_in[1];
  const float* Wh       = (const float*)d_in[2];
  const float* b_lstm   = (const float*)d_in[3];
  const float* W_params = (const float*)d_in[4];
  const float* b_params = (const float*)d_in[5];
  const float* W_out    = (const float*)d_in[6];
  const float* b_out    = (const float*)d_in[7];
  const int*   seqp     = (const int*)d_in[8];
  float* out = (float*)d_out;

  hipFuncSetAttribute((const void*)ntm_kernel,
                      hipFuncAttributeMaxDynamicSharedMemorySize, SMEM_BYTES);
  ntm_kernel<<<B_TOT / G, NTHR, SMEM_BYTES, stream>>>(
      inputs, Wx, Wh, b_lstm, W_params, b_params, W_out, b_out, seqp, out);
}

// Round 2
// 1896.967 us; speedup vs baseline: 1.9837x; 1.9837x over previous
//
#include <hip/hip_runtime.h>

namespace {

constexpr int B_TOT  = 2048;
constexpr int T_SEQ  = 66;
constexpr int IN_DIM = 9;
constexpr int H      = 100;
constexpr int N      = 128;
constexpr int D      = 20;
constexpr int OUTD   = 8;
constexpr int G      = 8;
constexpr int NTHR   = 1024;
constexpr float CLIPV = 20.0f;

constexpr int MSK    = N * D + 4;      // 2564: per-g M block stride (bank skew 4)
constexpr int WC_R   = 132;            // [Wx(29); Wh(100); b_lstm(1); 0(2)]
constexpr int WC_C   = 400;
constexpr int WP_R   = 108;            // [W_params(100); b_params(1); 0(7)]
constexpr int WP_C   = 92;
constexpr int WPOFF  = WC_R * WC_C;    // 52800 floats into ws

// ---- LDS layout (float words) ----
constexpr int OFF_M   = 0;                      // 8*2564 = 20512
constexpr int OFF_IN  = OFF_M + G * MSK;        // sIn_T [140][8]: rows 0..8 x, 9..28 r, 29..128 h, 129 one, 130.. zero
constexpr int OFF_C   = OFF_IN + 140 * 8;       // sc_T [100][8]
constexpr int OFF_FO  = OFF_C + 100 * 8;        // fo_T [100][18]  (f,o pairs, padded stride)
constexpr int OFF_P   = OFF_FO + 100 * 18;      // p_T [92][8]
constexpr int OFF_KV  = OFF_P + 92 * 8;         // [16][20]
constexpr int OFF_SC  = OFF_KV + 16 * 20;       // [16][8]
constexpr int OFF_EA  = OFF_SC + 16 * 8;        // [8][40]  e(20),a(20)
constexpr int OFF_MN  = OFF_EA + 8 * 40;        // [8][128]
constexpr int OFF_W   = OFF_MN + 8 * 128;       // [16][129]
constexpr int OFF_HO  = OFF_W + 16 * 129;       // [8][8]
constexpr int OFF_WO  = OFF_HO + 64;            // W_out [120][8]
constexpr int OFF_BO  = OFF_WO + 960;           // [8]
constexpr int OFF_OUT = OFF_BO + 8;             // souts, capacity 8*36*8 = 2304
constexpr int SMEM_FLOATS = OFF_OUT + 2304;     // 32160
constexpr int SMEM_BYTES  = SMEM_FLOATS * 4;    // 128640

__device__ __forceinline__ float fexp2(float x) { return __builtin_amdgcn_exp2f(x); }
__device__ __forceinline__ float flog2(float x) { return __builtin_amdgcn_logf(x); }
__device__ __forceinline__ float frcp(float x)  { return __builtin_amdgcn_rcpf(x); }
__device__ __forceinline__ float fexp(float x)  { return fexp2(x * 1.4426950408889634f); }
__device__ __forceinline__ float fsig(float x)  { return frcp(1.f + fexp2(-1.4426950408889634f * x)); }
__device__ __forceinline__ float ftanh(float x) { return 1.f - 2.f * frcp(1.f + fexp2(2.8853900817779268f * x)); }
__device__ __forceinline__ float fsoftplus(float x) { return log1pf(fexp(x)); }

template <int C>
__device__ __forceinline__ float dpp_add(float x) {
  return x + __int_as_float(__builtin_amdgcn_mov_dpp(__float_as_int(x), C, 0xF, 0xF, true));
}
// sum over the 4 lanes of a quad (xor1 then xor2)
__device__ __forceinline__ float qred(float x) { return dpp_add<0x4E>(dpp_add<0xB1>(x)); }

__device__ __forceinline__ float wred_max(float v) {
#pragma unroll
  for (int off = 32; off; off >>= 1) v = fmaxf(v, __shfl_xor(v, off, 64));
  return v;
}
__device__ __forceinline__ float wred_sum(float v) {
#pragma unroll
  for (int off = 32; off; off >>= 1) v += __shfl_xor(v, off, 64);
  return v;
}

#define FMA4(A, W, Hv)                      \
  do {                                      \
    A.x = fmaf(W, Hv.x, A.x);               \
    A.y = fmaf(W, Hv.y, A.y);               \
    A.z = fmaf(W, Hv.z, A.z);               \
    A.w = fmaf(W, Hv.w, A.w);               \
  } while (0)
#define RED4(A)                             \
  do {                                      \
    A.x = qred(A.x); A.y = qred(A.y);       \
    A.z = qred(A.z); A.w = qred(A.w);       \
  } while (0)

__global__ void setup_kernel(float* __restrict__ ws, const float* __restrict__ Wx,
                             const float* __restrict__ Wh, const float* __restrict__ b_lstm,
                             const float* __restrict__ Wp, const float* __restrict__ b_params) {
  int idx = blockIdx.x * blockDim.x + threadIdx.x;
  if (idx < WC_R * WC_C) {
    int r = idx / WC_C, c = idx - r * WC_C;
    float v = 0.f;
    if (r < 29) v = Wx[r * WC_C + c];
    else if (r < 129) v = Wh[(r - 29) * WC_C + c];
    else if (r == 129) v = b_lstm[c];
    ws[idx] = v;
  } else if (idx < WC_R * WC_C + WP_R * WP_C) {
    int i2 = idx - WPOFF;
    int r = i2 / WP_C, c = i2 - r * WP_C;
    float v = 0.f;
    if (r < 100) v = Wp[r * WP_C + c];
    else if (r == 100) v = b_params[c];
    ws[idx] = v;
  }
}

__global__ __launch_bounds__(NTHR, 1) void ntm_kernel(
    const float* __restrict__ inputs, const float* __restrict__ ws,
    const float* __restrict__ W_out, const float* __restrict__ b_out,
    const int* __restrict__ seqp, float* __restrict__ outp) {
  extern __shared__ float sm[];
  const int tid = threadIdx.x;
  const int b0 = blockIdx.x * G;
  const int tlim = seqp[0] + 1;
  const int TO = T_SEQ - tlim;
  const bool buffered = (TO <= 36);
  const float* Wc = ws;
  const float* Wp = ws + WPOFF;

  // ---------------- init ----------------
  for (int i = tid; i < G * MSK; i += NTHR) sm[OFF_M + i] = 1e-6f;
  for (int i = tid; i < 140 * 8; i += NTHR) {
    int row = i >> 3, g = i & 7;
    float v = 0.f;
    if (row < 9) v = inputs[(size_t)(b0 + g) * T_SEQ * IN_DIM + row];
    else if (row == 129) v = 1.f;
    sm[OFF_IN + i] = v;
  }
  for (int i = tid; i < 100 * 8; i += NTHR) sm[OFF_C + i] = 0.f;
  for (int i = tid; i < 16 * 129; i += NTHR) sm[OFF_W + i] = ((i % 129) == 0) ? 1.f : 0.f;
  for (int i = tid; i < 8 * 128; i += NTHR) sm[OFF_MN + i] = 4.47213595e-6f;
  for (int i = tid; i < 2304; i += NTHR) sm[OFF_OUT + i] = 0.f;
  if (tid < 960) sm[OFF_WO + tid] = W_out[tid];
  if (tid >= 960 && tid < 968) sm[OFF_BO + tid - 960] = b_out[tid - 960];
  __syncthreads();

  float4 aA0, aA1, aB0, aB1;  // phase-1 accumulators, live across barrier

  for (int t = 0; t < T_SEQ; ++t) {
    // ---------------- phase 1: gates GEMV (cols j2, j2+200; k-quarters) ----------------
    if (tid < 800) {
      const int j2 = tid >> 2, q = tid & 3;
      aA0 = make_float4(0.f, 0.f, 0.f, 0.f); aA1 = aA0; aB0 = aA0; aB1 = aA0;
      const float* wrow = Wc + (33 * q) * WC_C + j2;
      const float* hbase = &sm[OFF_IN + (33 * q) * 8];
#pragma unroll 4
      for (int i = 0; i < 33; ++i) {
        float w0 = wrow[i * WC_C];
        float w1 = wrow[i * WC_C + 200];
        float4 h0 = *(const float4*)(hbase + i * 8);
        float4 h1 = *(const float4*)(hbase + i * 8 + 4);
        FMA4(aA0, w0, h0); FMA4(aA1, w0, h1);
        FMA4(aB0, w1, h0); FMA4(aB1, w1, h1);
      }
      RED4(aA0); RED4(aA1); RED4(aB0); RED4(aB1);
      if (j2 >= 100) {  // this thread holds f (col j2) and o (col j2+200)
        int e = j2 - 100;
        float4 fa = (q & 2) ? aA1 : aA0;
        float4 ob = (q & 2) ? aB1 : aB0;
        float f0 = (q & 1) ? fa.z : fa.x, f1 = (q & 1) ? fa.w : fa.y;
        float o0 = (q & 1) ? ob.z : ob.x, o1 = (q & 1) ? ob.w : ob.y;
        float* fp = &sm[OFF_FO + e * 18 + 4 * q];
        *(float2*)fp = make_float2(f0, o0);
        *(float2*)(fp + 2) = make_float2(f1, o1);
      }
    }
    __syncthreads();  // B1

    // ---------------- phase 2: LSTM pointwise + x prefetch ----------------
    if (tid < 400) {
      const int e = tid >> 2, q = tid & 3;
      float4 ia = (q & 2) ? aA1 : aA0;
      float4 ga = (q & 2) ? aB1 : aB0;
      float i0 = (q & 1) ? ia.z : ia.x, i1 = (q & 1) ? ia.w : ia.y;
      float z0 = (q & 1) ? ga.z : ga.x, z1 = (q & 1) ? ga.w : ga.y;
      const float* fp = &sm[OFF_FO + e * 18 + 4 * q];
      float2 fo0 = *(const float2*)fp;
      float2 fo1 = *(const float2*)(fp + 2);
      float* cp = &sm[OFF_C + e * 8 + 2 * q];
      float2 c2 = *(const float2*)cp;
      float nc0 = fsig(fo0.x) * c2.x + fsig(i0) * ftanh(z0);
      float nc1 = fsig(fo1.x) * c2.y + fsig(i1) * ftanh(z1);
      float h0 = fsig(fo0.y) * ftanh(nc0);
      float h1 = fsig(fo1.y) * ftanh(nc1);
      *(float2*)cp = make_float2(nc0, nc1);
      *(float2*)&sm[OFF_IN + (29 + e) * 8 + 2 * q] = make_float2(h0, h1);
    } else if (tid >= 448 && tid < 520) {
      if (t + 1 < T_SEQ) {
        int p = tid - 448, g = p / 9, k = p - g * 9;
        sm[OFF_IN + k * 8 + g] =
            inputs[((size_t)(b0 + g) * T_SEQ + (t + 1)) * IN_DIM + k];
      }
    }
    __syncthreads();  // B2

    // ---------------- phase 3: p GEMV + hout ----------------
    if (tid < 184) {
      const int j2 = tid >> 2, q = tid & 3;
      float4 pA0 = make_float4(0.f, 0.f, 0.f, 0.f), pA1 = pA0, pB0 = pA0, pB1 = pA0;
      const float* wrow = Wp + (27 * q) * WP_C + j2;
      const float* hbase = &sm[OFF_IN + (29 + 27 * q) * 8];
#pragma unroll 4
      for (int i = 0; i < 27; ++i) {
        float w0 = wrow[i * WP_C];
        float w1 = wrow[i * WP_C + 46];
        float4 h0 = *(const float4*)(hbase + i * 8);
        float4 h1 = *(const float4*)(hbase + i * 8 + 4);
        FMA4(pA0, w0, h0); FMA4(pA1, w0, h1);
        FMA4(pB0, w1, h0); FMA4(pB1, w1, h1);
      }
      RED4(pA0); RED4(pA1); RED4(pB0); RED4(pB1);
      float4 pa = (q & 2) ? pA1 : pA0;
      float4 pb = (q & 2) ? pB1 : pB0;
      float a0 = (q & 1) ? pa.z : pa.x, a1 = (q & 1) ? pa.w : pa.y;
      float bb0 = (q & 1) ? pb.z : pb.x, bb1 = (q & 1) ? pb.w : pb.y;
      a0 = fminf(fmaxf(a0, -CLIPV), CLIPV); a1 = fminf(fmaxf(a1, -CLIPV), CLIPV);
      bb0 = fminf(fmaxf(bb0, -CLIPV), CLIPV); bb1 = fminf(fmaxf(bb1, -CLIPV), CLIPV);
      *(float2*)&sm[OFF_P + j2 * 8 + 2 * q] = make_float2(a0, a1);
      *(float2*)&sm[OFF_P + (j2 + 46) * 8 + 2 * q] = make_float2(bb0, bb1);
    } else if (tid >= 896 && tid < 960) {
      int g = (tid - 896) >> 3, o = tid & 7;
      float s = 0.f;
      for (int k = 0; k < H; ++k)
        s = fmaf(sm[OFF_IN + (29 + k) * 8 + g], sm[OFF_WO + k * 8 + o], s);
      sm[OFF_HO + g * 8 + o] = s;
    }
    __syncthreads();  // B3

    // ---------------- phase 4: per-head scalars / key / erase-add ----------------
    if (tid < 16) {
      int gh = tid, g = gh >> 1, hd = gh & 1;
      float ss = 0.f;
#pragma unroll
      for (int d = 0; d < D; ++d) {
        float kv = ftanh(sm[OFF_P + (hd * 26 + d) * 8 + g]);
        sm[OFF_KV + gh * 20 + d] = kv;
        ss = fmaf(kv, kv, ss);
      }
      float kn = sqrtf(ss);
      float beta = fsoftplus(sm[OFF_P + (hd * 26 + 20) * 8 + g]);
      float gg = fsig(sm[OFF_P + (hd * 26 + 21) * 8 + g]);
      float a0 = sm[OFF_P + (hd * 26 + 22) * 8 + g];
      float a1 = sm[OFF_P + (hd * 26 + 23) * 8 + g];
      float a2 = sm[OFF_P + (hd * 26 + 24) * 8 + g];
      float mx = fmaxf(a0, fmaxf(a1, a2));
      float e0 = fexp(a0 - mx), e1 = fexp(a1 - mx), e2 = fexp(a2 - mx);
      float inv = frcp(e0 + e1 + e2);
      float gamma = fsoftplus(sm[OFF_P + (hd * 26 + 25) * 8 + g]) + 1.f;
      float* scp = &sm[OFF_SC + gh * 8];
      scp[0] = beta; scp[1] = gg; scp[2] = e0 * inv; scp[3] = e1 * inv;
      scp[4] = e2 * inv; scp[5] = gamma; scp[6] = kn;
    } else if (tid >= 64 && tid < 384) {
      int p = tid - 64, g = p / 40, j = p - g * 40;
      float v = sm[OFF_P + (52 + j) * 8 + g];
      sm[OFF_EA + g * 40 + j] = (j < 20) ? fsig(v) : ftanh(v);
    }
    __syncthreads();  // B4

    // ---------------- phase 5: addressing, one wave per g, both heads ----------------
    if (tid < 512) {
      const int g = tid >> 6, l = tid & 63;
      float4 k0[5], k1[5];
#pragma unroll
      for (int d = 0; d < 5; ++d) {
        k0[d] = *(const float4*)&sm[OFF_KV + (2 * g) * 20 + d * 4];
        k1[d] = *(const float4*)&sm[OFF_KV + (2 * g + 1) * 20 + d * 4];
      }
      const float* M0 = &sm[OFF_M + g * MSK + l * 20];
      const float* M1 = M0 + 64 * 20;
      float dh0n0 = 0.f, dh0n1 = 0.f, dh1n0 = 0.f, dh1n1 = 0.f;
#pragma unroll
      for (int d = 0; d < 5; ++d) {
        float4 m0 = *(const float4*)(M0 + d * 4);
        float4 m1 = *(const float4*)(M1 + d * 4);
        dh0n0 = fmaf(m0.x, k0[d].x, fmaf(m0.y, k0[d].y, fmaf(m0.z, k0[d].z, fmaf(m0.w, k0[d].w, dh0n0))));
        dh1n0 = fmaf(m0.x, k1[d].x, fmaf(m0.y, k1[d].y, fmaf(m0.z, k1[d].z, fmaf(m0.w, k1[d].w, dh1n0))));
        dh0n1 = fmaf(m1.x, k0[d].x, fmaf(m1.y, k0[d].y, fmaf(m1.z, k0[d].z, fmaf(m1.w, k0[d].w, dh0n1))));
        dh1n1 = fmaf(m1.x, k1[d].x, fmaf(m1.y, k1[d].y, fmaf(m1.z, k1[d].z, fmaf(m1.w, k1[d].w, dh1n1))));
      }
      float Mn0 = sm[OFF_MN + g * 128 + l];
      float Mn1 = sm[OFF_MN + g * 128 + 64 + l];

      auto head = [&](int gh, float dot0, float dot1) {
        const float* scp = &sm[OFF_SC + gh * 8];
        float beta = scp[0], gg = scp[1], s0 = scp[2], s1 = scp[3], s2 = scp[4];
        float gamma = scp[5], kn = scp[6];
        float S0 = beta * dot0 * frcp(kn * Mn0 + 1e-8f);
        float S1 = beta * dot1 * frcp(kn * Mn1 + 1e-8f);
        float mx = wred_max(fmaxf(S0, S1));
        float e0 = fexp(S0 - mx), e1 = fexp(S1 - mx);
        float sinv = frcp(wred_sum(e0 + e1));
        float* wp = &sm[OFF_W + gh * 129];
        float wp0 = wp[l], wp1 = wp[64 + l];
        float wg0 = fmaf(gg, e0 * sinv - wp0, wp0);
        float wg1 = fmaf(gg, e1 * sinv - wp1, wp1);
        int lp = (l + 1) & 63, lm = (l + 63) & 63;
        float n0a = __shfl(wg0, lp, 64), n1a = __shfl(wg1, lp, 64);
        float p0a = __shfl(wg0, lm, 64), p1a = __shfl(wg1, lm, 64);
        float w1l0 = __shfl(wg1, 0, 64);
        float w0l0 = __shfl(wg0, 0, 64);
        float w0l63 = __shfl(wg0, 63, 64);
        float w1l63 = __shfl(wg1, 63, 64);
        float nxt0 = (l == 63) ? w1l0 : n0a;   // wg(l+1)
        float nxt1 = (l == 63) ? w0l0 : n1a;   // wg(65+l) wraps to wg(0)
        float prv0 = (l == 0) ? w1l63 : p0a;   // wg(l-1) wraps to wg(127)
        float prv1 = (l == 0) ? w0l63 : p1a;   // wg(63+l)
        float wt0 = fmaxf(fmaf(s0, nxt0, fmaf(s1, wg0, s2 * prv0)), 1e-16f);
        float wt1 = fmaxf(fmaf(s0, nxt1, fmaf(s1, wg1, s2 * prv1)), 1e-16f);
        float invm = frcp(wred_max(fmaxf(wt0, wt1)));
        float q0 = fexp2(gamma * flog2(wt0 * invm));
        float q1 = fexp2(gamma * flog2(wt1 * invm));
        float pinv = frcp(wred_sum(q0 + q1));
        wp[l] = q0 * pinv;
        wp[64 + l] = q1 * pinv;
      };
      head(2 * g, dh0n0, dh0n1);
      head(2 * g + 1, dh1n0, dh1n1);
    }
    __syncthreads();  // B5

    // ---------------- phase 6: r_new = w_r @ M ----------------
    if (tid < 640) {
      int idx = tid >> 2, nq = tid & 3;
      int g = idx / 20, d = idx - g * 20;
      const float* wr = &sm[OFF_W + (2 * g) * 129];
      const float* Mg = &sm[OFF_M + g * MSK];
      float s = 0.f;
#pragma unroll 8
      for (int i = 0; i < 32; ++i) {
        int n = nq + 4 * i;
        s = fmaf(wr[n], Mg[n * 20 + d], s);
      }
      s = qred(s);
      if (nq == 0) sm[OFF_IN + (9 + d) * 8 + g] = s;
    }
    __syncthreads();  // B6

    // ---------------- phase 7: M update + norm; output ----------------
    {
      int g = tid >> 7, n = tid & 127;
      float ww = sm[OFF_W + (2 * g + 1) * 129 + n];
      const float* ep = &sm[OFF_EA + g * 40];
      const float* ap = ep + 20;
      float* Mr = &sm[OFF_M + g * MSK + n * 20];
      float nrm = 0.f;
#pragma unroll
      for (int d4 = 0; d4 < 5; ++d4) {
        float4 m = *(const float4*)(Mr + d4 * 4);
        float4 e = *(const float4*)(ep + d4 * 4);
        float4 a = *(const float4*)(ap + d4 * 4);
        m.x = fmaf(ww, fmaf(-e.x, m.x, a.x), m.x);
        m.y = fmaf(ww, fmaf(-e.y, m.y, a.y), m.y);
        m.z = fmaf(ww, fmaf(-e.z, m.z, a.z), m.z);
        m.w = fmaf(ww, fmaf(-e.w, m.w, a.w), m.w);
        nrm = fmaf(m.x, m.x, fmaf(m.y, m.y, fmaf(m.z, m.z, fmaf(m.w, m.w, nrm))));
        *(float4*)(Mr + d4 * 4) = m;
      }
      sm[OFF_MN + g * 128 + n] = sqrtf(nrm);
    }
    if (t >= tlim && tid < 64) {
      int g = tid >> 3, o = tid & 7;
      float s = sm[OFF_HO + g * 8 + o] + sm[OFF_BO + o];
#pragma unroll
      for (int d = 0; d < D; ++d)
        s = fmaf(sm[OFF_IN + (9 + d) * 8 + g], sm[OFF_WO + (100 + d) * 8 + o], s);
      s = fminf(fmaxf(s, -CLIPV), CLIPV);
      float val = fsig(s);
      int tp = t - tlim;
      if (buffered) sm[OFF_OUT + (g * TO + tp) * 8 + o] = val;
      else outp[((size_t)(b0 + g) * TO + tp) * 8 + o] = val;
    }
    __syncthreads();  // B7
  }

  // ---------------- coalesced output flush ----------------
  if (buffered) {
    const int total = G * TO * 8;
    for (int i = tid * 4; i < total; i += NTHR * 4) {
      float4 v = *(const float4*)&sm[OFF_OUT + i];
      *(float4*)&outp[(size_t)blockIdx.x * total + i] = v;
    }
  }
}

}  // namespace

extern "C" void kernel_launch(void* const* d_in, const int* in_sizes, int n_in,
                              void* d_out, int out_size, void* d_ws, size_t ws_size,
                              hipStream_t stream) {
  (void)in_sizes; (void)n_in; (void)out_size; (void)ws_size;
  const float* inputs   = (const float*)d_in[0];
  const float* Wx       = (const float*)d_in[1];
  const float* Wh       = (const float*)d_in[2];
  const float* b_lstm   = (const float*)d_in[3];
  const float* W_params = (const float*)d_in[4];
  const float* b_params = (const float*)d_in[5];
  const float* W_out    = (const float*)d_in[6];
  const float* b_out    = (const float*)d_in[7];
  const int*   seqp     = (const int*)d_in[8];
  float* out = (float*)d_out;
  float* ws  = (float*)d_ws;

  constexpr int SETUP_N = WC_R * WC_C + WP_R * WP_C;
  setup_kernel<<<(SETUP_N + 255) / 256, 256, 0, stream>>>(ws, Wx, Wh, b_lstm,
                                                          W_params, b_params);

  hipFuncSetAttribute((const void*)ntm_kernel,
                      hipFuncAttributeMaxDynamicSharedMemorySize, SMEM_BYTES);
  ntm_kernel<<<B_TOT / G, NTHR, SMEM_BYTES, stream>>>(inputs, ws, W_out, b_out,
                                                      seqp, out);
}

// Round 3
// 1290.940 us; speedup vs baseline: 2.9149x; 1.4694x over previous
//
#include <hip/hip_runtime.h>

namespace {

constexpr int B_TOT  = 2048;
constexpr int T_SEQ  = 66;
constexpr int IN_DIM = 9;
constexpr int H      = 100;
constexpr int N      = 128;
constexpr int D      = 20;
constexpr int OUTD   = 8;
constexpr int G      = 4;      // sequences per block
constexpr int NTHR   = 512;    // 8 waves -> 2 blocks/CU
constexpr float CLIPV = 20.0f;

constexpr int MSK    = N * D + 4;      // 2564 floats per-g M block (inter-g skew)
constexpr int WC_R   = 132;            // [Wx(29); Wh(100); b_lstm(1); 0(2)]
constexpr int WC_C   = 400;
constexpr int WP_C   = 92;             // [W_params(100); b_params(1); 0(7)]
constexpr int WP_R   = 108;
constexpr int WPOFF  = WC_R * WC_C;    // 52800

// ---- LDS layout (float words) ----
constexpr int OFF_M   = 0;                      // G*MSK = 10256
constexpr int OFF_IN  = OFF_M + G * MSK;        // [132][G]: 0-8 x, 9-28 r, 29-128 h, 129 one, 130-131 zero
constexpr int OFF_C   = OFF_IN + 132 * G;       // [100][G]
constexpr int OFF_FO  = OFF_C + 100 * G;        // [100][8]: f[4], o[4]
constexpr int OFF_P   = OFF_FO + 100 * 8;       // [92][G]
constexpr int OFF_KV  = OFF_P + 92 * G;         // [8][20]
constexpr int OFF_SC  = OFF_KV + 8 * 20;        // [8][8]
constexpr int OFF_EA  = OFF_SC + 8 * 8;         // [G][40] e(20),a(20)
constexpr int OFF_MN  = OFF_EA + G * 40;        // [G][128]
constexpr int OFF_W   = OFF_MN + G * N;         // [8][129]
constexpr int OFF_HO  = OFF_W + 8 * 129;        // [G][8]
constexpr int OFF_WO  = OFF_HO + G * 8;         // W_out [120][8]
constexpr int OFF_BO  = OFF_WO + 960;           // [8]
constexpr int OFF_OUT = OFF_BO + 8;             // [G*36*8] = 1152
constexpr int SMEM_FLOATS = OFF_OUT + G * 36 * 8;   // 16432
constexpr int SMEM_BYTES  = SMEM_FLOATS * 4;        // 65728 B -> 2 blocks/CU

__device__ __forceinline__ float fexp2(float x) { return __builtin_amdgcn_exp2f(x); }
__device__ __forceinline__ float flog2(float x) { return __builtin_amdgcn_logf(x); }
__device__ __forceinline__ float frcp(float x)  { return __builtin_amdgcn_rcpf(x); }
__device__ __forceinline__ float fexp(float x)  { return fexp2(x * 1.4426950408889634f); }
__device__ __forceinline__ float fsig(float x)  { return frcp(1.f + fexp2(-1.4426950408889634f * x)); }
__device__ __forceinline__ float ftanh(float x) { return 1.f - 2.f * frcp(1.f + fexp2(2.8853900817779268f * x)); }
__device__ __forceinline__ float fsoftplus(float x) { return log1pf(fexp(x)); }

template <int C>
__device__ __forceinline__ float dpp_add(float x) {
  return x + __int_as_float(__builtin_amdgcn_mov_dpp(__float_as_int(x), C, 0xF, 0xF, true));
}
__device__ __forceinline__ float pred(float x) { return dpp_add<0xB1>(x); }            // pair (xor1)
__device__ __forceinline__ float qred(float x) { return dpp_add<0x4E>(dpp_add<0xB1>(x)); }  // quad

__device__ __forceinline__ float wred_max(float v) {
#pragma unroll
  for (int off = 32; off; off >>= 1) v = fmaxf(v, __shfl_xor(v, off, 64));
  return v;
}
__device__ __forceinline__ float wred_sum(float v) {
#pragma unroll
  for (int off = 32; off; off >>= 1) v += __shfl_xor(v, off, 64);
  return v;
}

#define FMA4(A, W, Hv)                      \
  do {                                      \
    A.x = fmaf(W, Hv.x, A.x);               \
    A.y = fmaf(W, Hv.y, A.y);               \
    A.z = fmaf(W, Hv.z, A.z);               \
    A.w = fmaf(W, Hv.w, A.w);               \
  } while (0)

__global__ void setup_kernel(float* __restrict__ ws, const float* __restrict__ Wx,
                             const float* __restrict__ Wh, const float* __restrict__ b_lstm,
                             const float* __restrict__ Wp, const float* __restrict__ b_params) {
  int idx = blockIdx.x * blockDim.x + threadIdx.x;
  if (idx < WC_R * WC_C) {
    int r = idx / WC_C, c = idx - r * WC_C;
    float v = 0.f;
    if (r < 29) v = Wx[r * WC_C + c];
    else if (r < 129) v = Wh[(r - 29) * WC_C + c];
    else if (r == 129) v = b_lstm[c];
    ws[idx] = v;
  } else if (idx < WC_R * WC_C + WP_R * WP_C) {
    int i2 = idx - WPOFF;
    int r = i2 / WP_C, c = i2 - r * WP_C;
    float v = 0.f;
    if (r < 100) v = Wp[r * WP_C + c];
    else if (r == 100) v = b_params[c];
    ws[idx] = v;
  }
}

__global__ __launch_bounds__(NTHR, 4) void ntm_kernel(
    const float* __restrict__ inputs, const float* __restrict__ ws,
    const float* __restrict__ W_out, const float* __restrict__ b_out,
    const int* __restrict__ seqp, float* __restrict__ outp) {
  extern __shared__ float sm[];
  const int tid = threadIdx.x;
  const int b0 = blockIdx.x * G;
  const int tlim = seqp[0] + 1;
  const int TO = T_SEQ - tlim;
  const bool buffered = (TO <= 36);
  const float* Wc = ws;
  const float* Wp = ws + WPOFF;

  // ---------------- init ----------------
  for (int i = tid; i < G * MSK; i += NTHR) sm[OFF_M + i] = 1e-6f;
  for (int i = tid; i < 132 * G; i += NTHR) {
    int row = i >> 2, g = i & 3;
    float v = 0.f;
    if (row < IN_DIM) v = inputs[(size_t)(b0 + g) * T_SEQ * IN_DIM + row];
    else if (row == 129) v = 1.f;
    sm[OFF_IN + i] = v;
  }
  for (int i = tid; i < H * G; i += NTHR) sm[OFF_C + i] = 0.f;
  for (int i = tid; i < 8 * 129; i += NTHR) sm[OFF_W + i] = ((i % 129) == 0) ? 1.f : 0.f;
  for (int i = tid; i < G * N; i += NTHR) sm[OFF_MN + i] = 4.47213595e-6f;
  for (int i = tid; i < G * 36 * 8; i += NTHR) sm[OFF_OUT + i] = 0.f;
  for (int i = tid; i < 960; i += NTHR) sm[OFF_WO + i] = W_out[i];
  if (tid < 8) sm[OFF_BO + tid] = b_out[tid];
  __syncthreads();

  float4 aA, aB;  // gates accumulators, live across B1

  for (int t = 0; t < T_SEQ; ++t) {
    // ---- P1: gates GEMV. thread (j2,q): cols {j2, j2+200}, rows 66q..66q+65 ----
    if (tid < 400) {
      const int j2 = tid >> 1, q = tid & 1;
      aA = make_float4(0.f, 0.f, 0.f, 0.f); aB = aA;
      const float* wr = Wc + (66 * q) * WC_C + j2;
      const float* hb = &sm[OFF_IN + (66 * q) * 4];
#pragma unroll 6
      for (int i = 0; i < 66; ++i) {
        float w0 = wr[i * WC_C];
        float w1 = wr[i * WC_C + 200];
        float4 h = *(const float4*)(hb + i * 4);
        FMA4(aA, w0, h); FMA4(aB, w1, h);
      }
      aA.x = pred(aA.x); aA.y = pred(aA.y); aA.z = pred(aA.z); aA.w = pred(aA.w);
      aB.x = pred(aB.x); aB.y = pred(aB.y); aB.z = pred(aB.z); aB.w = pred(aB.w);
      if (j2 >= 100 && q == 0) {  // publish f,o
        int e = j2 - 100;
        *(float4*)&sm[OFF_FO + e * 8] = aA;
        *(float4*)&sm[OFF_FO + e * 8 + 4] = aB;
      }
    }
    __syncthreads();  // B1

    // ---- P2: LSTM pointwise (thread (e,q): seqs 2q,2q+1) + x prefetch ----
    if (tid < 200) {
      const int e = tid >> 1, q = tid & 1;
      float i0 = q ? aA.z : aA.x, i1 = q ? aA.w : aA.y;
      float z0 = q ? aB.z : aB.x, z1 = q ? aB.w : aB.y;
      float2 f2 = *(const float2*)&sm[OFF_FO + e * 8 + 2 * q];
      float2 o2 = *(const float2*)&sm[OFF_FO + e * 8 + 4 + 2 * q];
      float2 c2 = *(const float2*)&sm[OFF_C + e * 4 + 2 * q];
      float nc0 = fsig(f2.x) * c2.x + fsig(i0) * ftanh(z0);
      float nc1 = fsig(f2.y) * c2.y + fsig(i1) * ftanh(z1);
      float h0 = fsig(o2.x) * ftanh(nc0);
      float h1 = fsig(o2.y) * ftanh(nc1);
      *(float2*)&sm[OFF_C + e * 4 + 2 * q] = make_float2(nc0, nc1);
      *(float2*)&sm[OFF_IN + (29 + e) * 4 + 2 * q] = make_float2(h0, h1);
    } else if (tid >= 448 && tid < 484) {
      if (t + 1 < T_SEQ) {
        int p = tid - 448, g = p / 9, k = p - g * 9;
        sm[OFF_IN + k * 4 + g] =
            inputs[((size_t)(b0 + g) * T_SEQ + (t + 1)) * IN_DIM + k];
      }
    }
    __syncthreads();  // B2

    // ---- P3: p GEMV (thread (j,q): col j, rows 25q..25q+24) + hout ----
    if (tid < 368) {
      const int j = tid >> 2, q = tid & 3;
      float bv = (q == 0) ? Wp[100 * WP_C + j] : 0.f;
      float4 acc = make_float4(bv, bv, bv, bv);
      const float* wr = Wp + (25 * q) * WP_C + j;
      const float* hb = &sm[OFF_IN + (29 + 25 * q) * 4];
#pragma unroll 5
      for (int i = 0; i < 25; ++i) {
        float w0 = wr[i * WP_C];
        float4 h = *(const float4*)(hb + i * 4);
        FMA4(acc, w0, h);
      }
      acc.x = qred(acc.x); acc.y = qred(acc.y); acc.z = qred(acc.z); acc.w = qred(acc.w);
      if (q == 0) {
        acc.x = fminf(fmaxf(acc.x, -CLIPV), CLIPV);
        acc.y = fminf(fmaxf(acc.y, -CLIPV), CLIPV);
        acc.z = fminf(fmaxf(acc.z, -CLIPV), CLIPV);
        acc.w = fminf(fmaxf(acc.w, -CLIPV), CLIPV);
        *(float4*)&sm[OFF_P + j * 4] = acc;
      }
    } else if (tid >= 448) {
      int p = tid - 448;
      int g = p >> 4, o = (p >> 1) & 7, hf = p & 1;
      const float* hb = &sm[OFF_IN + (29 + 50 * hf) * 4 + g];
      const float* wo = &sm[OFF_WO + (50 * hf) * 8 + o];
      float s = 0.f;
#pragma unroll 10
      for (int k = 0; k < 50; ++k) s = fmaf(hb[k * 4], wo[k * 8], s);
      s = pred(s);
      if (hf == 0) sm[OFF_HO + g * 8 + o] = s;
    }
    __syncthreads();  // B3

    // ---- P5: addressing. wave w = (g = w>>1, head = w&1); in-wave scalar prep ----
    {
      const int w = tid >> 6, l = tid & 63;
      const int g = w >> 1, hd = w & 1, gh = w;
      if (l < 20) {
        sm[OFF_KV + gh * 20 + l] = ftanh(sm[OFF_P + (hd * 26 + l) * 4 + g]);
      } else if (l < 26) {
        int which = l - 20;
        float v = sm[OFF_P + (hd * 26 + 20 + which) * 4 + g];
        if (which == 0) sm[OFF_SC + gh * 8 + 0] = fsoftplus(v);
        else if (which == 1) sm[OFF_SC + gh * 8 + 1] = fsig(v);
        else if (which == 2) {
          float a1 = sm[OFF_P + (hd * 26 + 23) * 4 + g];
          float a2 = sm[OFF_P + (hd * 26 + 24) * 4 + g];
          float mx = fmaxf(v, fmaxf(a1, a2));
          float e0 = fexp(v - mx), e1 = fexp(a1 - mx), e2 = fexp(a2 - mx);
          float inv = frcp(e0 + e1 + e2);
          sm[OFF_SC + gh * 8 + 2] = e0 * inv;
          sm[OFF_SC + gh * 8 + 3] = e1 * inv;
          sm[OFF_SC + gh * 8 + 4] = e2 * inv;
        } else if (which == 5) {
          sm[OFF_SC + gh * 8 + 5] = fsoftplus(v) + 1.f;
        }
      }
      asm volatile("s_waitcnt lgkmcnt(0)" ::: "memory");  // wave-internal publish

      float4 kk[5];
#pragma unroll
      for (int i = 0; i < 5; ++i) kk[i] = *(const float4*)&sm[OFF_KV + gh * 20 + i * 4];
      float kn = 0.f;
#pragma unroll
      for (int i = 0; i < 5; ++i)
        kn = fmaf(kk[i].x, kk[i].x, fmaf(kk[i].y, kk[i].y,
             fmaf(kk[i].z, kk[i].z, fmaf(kk[i].w, kk[i].w, kn))));
      kn = sqrtf(kn);
      const float* M0 = &sm[OFF_M + g * MSK + l * 20];
      const float* M1 = M0 + 64 * 20;
      float d0 = 0.f, d1 = 0.f;
#pragma unroll
      for (int i = 0; i < 5; ++i) {
        float4 m0 = *(const float4*)(M0 + i * 4);
        float4 m1 = *(const float4*)(M1 + i * 4);
        d0 = fmaf(m0.x, kk[i].x, fmaf(m0.y, kk[i].y, fmaf(m0.z, kk[i].z, fmaf(m0.w, kk[i].w, d0))));
        d1 = fmaf(m1.x, kk[i].x, fmaf(m1.y, kk[i].y, fmaf(m1.z, kk[i].z, fmaf(m1.w, kk[i].w, d1))));
      }
      float Mn0 = sm[OFF_MN + g * N + l];
      float Mn1 = sm[OFF_MN + g * N + 64 + l];
      const float* scp = &sm[OFF_SC + gh * 8];
      float beta = scp[0], gg = scp[1], s0 = scp[2], s1 = scp[3], s2 = scp[4];
      float gamma = scp[5];
      float S0 = beta * d0 * frcp(kn * Mn0 + 1e-8f);
      float S1 = beta * d1 * frcp(kn * Mn1 + 1e-8f);
      float mx = wred_max(fmaxf(S0, S1));
      float e0 = fexp(S0 - mx), e1 = fexp(S1 - mx);
      float sinv = frcp(wred_sum(e0 + e1));
      float* wp = &sm[OFF_W + gh * 129];
      float wp0 = wp[l], wp1 = wp[64 + l];
      float wg0 = fmaf(gg, e0 * sinv - wp0, wp0);
      float wg1 = fmaf(gg, e1 * sinv - wp1, wp1);
      int lp = (l + 1) & 63, lm = (l + 63) & 63;
      float n0a = __shfl(wg0, lp, 64), n1a = __shfl(wg1, lp, 64);
      float p0a = __shfl(wg0, lm, 64), p1a = __shfl(wg1, lm, 64);
      float w1l0 = __shfl(wg1, 0, 64);
      float w0l0 = __shfl(wg0, 0, 64);
      float w0l63 = __shfl(wg0, 63, 64);
      float w1l63 = __shfl(wg1, 63, 64);
      float nxt0 = (l == 63) ? w1l0 : n0a;
      float nxt1 = (l == 63) ? w0l0 : n1a;
      float prv0 = (l == 0) ? w1l63 : p0a;
      float prv1 = (l == 0) ? w0l63 : p1a;
      float wt0 = fmaxf(fmaf(s0, nxt0, fmaf(s1, wg0, s2 * prv0)), 1e-16f);
      float wt1 = fmaxf(fmaf(s0, nxt1, fmaf(s1, wg1, s2 * prv1)), 1e-16f);
      float invm = frcp(wred_max(fmaxf(wt0, wt1)));
      float q0 = fexp2(gamma * flog2(wt0 * invm));
      float q1 = fexp2(gamma * flog2(wt1 * invm));
      float pinv = frcp(wred_sum(q0 + q1));
      wp[l] = q0 * pinv;
      wp[64 + l] = q1 * pinv;
    }
    __syncthreads();  // B5

    // ---- P6: r_new = w_r @ M ; e/a activations ----
    if (tid < 320) {
      int idx = tid >> 2, nq = tid & 3;
      int g = idx / 20, d = idx - g * 20;
      const float* wr = &sm[OFF_W + (2 * g) * 129];
      const float* Mg = &sm[OFF_M + g * MSK];
      float s = 0.f;
#pragma unroll 8
      for (int i = 0; i < 32; ++i) {
        int n = nq + 4 * i;
        s = fmaf(wr[n], Mg[n * 20 + d], s);
      }
      s = qred(s);
      if (nq == 0) sm[OFF_IN + (9 + d) * 4 + g] = s;
    } else if (tid < 480) {
      int p = tid - 320, g = p / 40, j = p - g * 40;
      float v = sm[OFF_P + (52 + j) * 4 + g];
      sm[OFF_EA + g * 40 + j] = (j < 20) ? fsig(v) : ftanh(v);
    }
    __syncthreads();  // B6

    // ---- P7: M update + norm ; output ----
    {
      int g = tid >> 7, n = tid & 127;
      float ww = sm[OFF_W + (2 * g + 1) * 129 + n];
      const float* ep = &sm[OFF_EA + g * 40];
      const float* ap = ep + 20;
      float* Mr = &sm[OFF_M + g * MSK + n * 20];
      float nrm = 0.f;
#pragma unroll
      for (int d4 = 0; d4 < 5; ++d4) {
        float4 m = *(const float4*)(Mr + d4 * 4);
        float4 e = *(const float4*)(ep + d4 * 4);
        float4 a = *(const float4*)(ap + d4 * 4);
        m.x = fmaf(ww, fmaf(-e.x, m.x, a.x), m.x);
        m.y = fmaf(ww, fmaf(-e.y, m.y, a.y), m.y);
        m.z = fmaf(ww, fmaf(-e.z, m.z, a.z), m.z);
        m.w = fmaf(ww, fmaf(-e.w, m.w, a.w), m.w);
        nrm = fmaf(m.x, m.x, fmaf(m.y, m.y, fmaf(m.z, m.z, fmaf(m.w, m.w, nrm))));
        *(float4*)(Mr + d4 * 4) = m;
      }
      sm[OFF_MN + g * N + n] = sqrtf(nrm);
    }
    if (t >= tlim && tid < 32) {
      int g = tid >> 3, o = tid & 7;
      float s = sm[OFF_HO + g * 8 + o] + sm[OFF_BO + o];
#pragma unroll
      for (int d = 0; d < D; ++d)
        s = fmaf(sm[OFF_IN + (9 + d) * 4 + g], sm[OFF_WO + (100 + d) * 8 + o], s);
      s = fminf(fmaxf(s, -CLIPV), CLIPV);
      float val = fsig(s);
      int tp = t - tlim;
      if (buffered) sm[OFF_OUT + (g * TO + tp) * 8 + o] = val;
      else outp[((size_t)(b0 + g) * TO + tp) * 8 + o] = val;
    }
    __syncthreads();  // B7
  }

  // ---- coalesced output flush ----
  if (buffered) {
    const int total = G * TO * 8;
    for (int i = tid * 4; i < total; i += NTHR * 4) {
      float4 v = *(const float4*)&sm[OFF_OUT + i];
      *(float4*)&outp[(size_t)blockIdx.x * total + i] = v;
    }
  }
}

}  // namespace

extern "C" void kernel_launch(void* const* d_in, const int* in_sizes, int n_in,
                              void* d_out, int out_size, void* d_ws, size_t ws_size,
                              hipStream_t stream) {
  (void)in_sizes; (void)n_in; (void)out_size; (void)ws_size;
  const float* inputs   = (const float*)d_in[0];
  const float* Wx       = (const float*)d_in[1];
  const float* Wh       = (const float*)d_in[2];
  const float* b_lstm   = (const float*)d_in[3];
  const float* W_params = (const float*)d_in[4];
  const float* b_params = (const float*)d_in[5];
  const float* W_out    = (const float*)d_in[6];
  const float* b_out    = (const float*)d_in[7];
  const int*   seqp     = (const int*)d_in[8];
  float* out = (float*)d_out;
  float* ws  = (float*)d_ws;

  constexpr int SETUP_N = WC_R * WC_C + WP_R * WP_C;
  setup_kernel<<<(SETUP_N + 255) / 256, 256, 0, stream>>>(ws, Wx, Wh, b_lstm,
                                                          W_params, b_params);

  hipFuncSetAttribute((const void*)ntm_kernel,
                      hipFuncAttributeMaxDynamicSharedMemorySize, SMEM_BYTES);
  ntm_kernel<<<B_TOT / G, NTHR, SMEM_BYTES, stream>>>(inputs, ws, W_out, b_out,
                                                      seqp, out);
}

// Round 4
// 1145.190 us; speedup vs baseline: 3.2859x; 1.1273x over previous
//
#include <hip/hip_runtime.h>

namespace {

constexpr int B_TOT  = 2048;
constexpr int T_SEQ  = 66;
constexpr int IN_DIM = 9;
constexpr int H      = 100;
constexpr int N      = 128;
constexpr int D      = 20;
constexpr int OUTD   = 8;
constexpr int G      = 4;      // sequences per block
constexpr int NTHR   = 512;    // 8 waves: 0-3 critical path, 4-7 background GEMV
constexpr float CLIPV = 20.0f;

constexpr int WC_R = 132;   // staged [Wx(29); Wh(100); b_lstm(1); 0(2)] x 400
constexpr int WC_C = 400;
constexpr int WP_R = 108;   // staged [W_params(100); b_params(1); 0(7)] x 92
constexpr int WP_C = 92;
constexpr int WPOFF = WC_R * WC_C;

constexpr int MT_ROW = 132;             // M transposed [d][n], n padded to 132
constexpr int MSKT   = D * MT_ROW + 4;  // per-g stride (skew)

// ---- LDS layout (float words) ----
constexpr int OFF_M   = 0;                    // [G][20][132] transposed M
constexpr int OFF_IN  = OFF_M + G * MSKT;     // [120][4]: rows 0-19 r, 20-119 h
constexpr int OFF_XS  = OFF_IN + 120 * 4;     // [9][4] x staging
constexpr int OFF_GT  = OFF_XS + 36;          // [400][4] gates
constexpr int OFF_C   = OFF_GT + 1600;        // [100][4]
constexpr int OFF_P   = OFF_C + 400;          // [92][4]
constexpr int OFF_KV  = OFF_P + 368;          // [8][20]
constexpr int OFF_SC  = OFF_KV + 160;         // [8][8]
constexpr int OFF_EA  = OFF_SC + 64;          // [4][40] e(20),a(20)
constexpr int OFF_MN  = OFF_EA + 160;         // [4][128]
constexpr int OFF_W   = OFF_MN + 512;         // [8][129]
constexpr int OFF_HO  = OFF_W + 1032;         // [4][8]
constexpr int OFF_WO  = OFF_HO + 32;          // W_out [120][8]
constexpr int OFF_BO  = OFF_WO + 960;         // [8]
constexpr int OFF_OUT = OFF_BO + 8;           // [4*36*8]
constexpr int SMEM_FLOATS = OFF_OUT + G * 36 * 8;   // 17540
constexpr int SMEM_BYTES  = SMEM_FLOATS * 4;        // 70160 -> 2 blocks/CU

__device__ __forceinline__ float fexp2(float x) { return __builtin_amdgcn_exp2f(x); }
__device__ __forceinline__ float flog2(float x) { return __builtin_amdgcn_logf(x); }
__device__ __forceinline__ float frcp(float x)  { return __builtin_amdgcn_rcpf(x); }
__device__ __forceinline__ float fexp(float x)  { return fexp2(x * 1.4426950408889634f); }
__device__ __forceinline__ float fsig(float x)  { return frcp(1.f + fexp2(-1.4426950408889634f * x)); }
__device__ __forceinline__ float ftanh(float x) { return 1.f - 2.f * frcp(1.f + fexp2(2.8853900817779268f * x)); }
__device__ __forceinline__ float fsoftplus(float x) { return log1pf(fexp(x)); }

template <int C>
__device__ __forceinline__ float dpp_add(float x) {
  return x + __int_as_float(__builtin_amdgcn_mov_dpp(__float_as_int(x), C, 0xF, 0xF, true));
}
__device__ __forceinline__ float pred(float x) { return dpp_add<0xB1>(x); }  // lane-pair sum

__device__ __forceinline__ void wred_max2(float& a, float& b) {
#pragma unroll
  for (int off = 32; off; off >>= 1) {
    a = fmaxf(a, __shfl_xor(a, off, 64));
    b = fmaxf(b, __shfl_xor(b, off, 64));
  }
}
__device__ __forceinline__ void wred_sum2(float& a, float& b) {
#pragma unroll
  for (int off = 32; off; off >>= 1) {
    a += __shfl_xor(a, off, 64);
    b += __shfl_xor(b, off, 64);
  }
}

#define FMA4(A, W, Hv)                      \
  do {                                      \
    A.x = fmaf(W, Hv.x, A.x);               \
    A.y = fmaf(W, Hv.y, A.y);               \
    A.z = fmaf(W, Hv.z, A.z);               \
    A.w = fmaf(W, Hv.w, A.w);               \
  } while (0)

__global__ void setup_kernel(float* __restrict__ ws, const float* __restrict__ Wx,
                             const float* __restrict__ Wh, const float* __restrict__ b_lstm,
                             const float* __restrict__ Wp, const float* __restrict__ b_params) {
  int idx = blockIdx.x * blockDim.x + threadIdx.x;
  if (idx < WC_R * WC_C) {
    int r = idx / WC_C, c = idx - r * WC_C;
    float v = 0.f;
    if (r < 29) v = Wx[r * WC_C + c];
    else if (r < 129) v = Wh[(r - 29) * WC_C + c];
    else if (r == 129) v = b_lstm[c];
    ws[idx] = v;
  } else if (idx < WC_R * WC_C + WP_R * WP_C) {
    int i2 = idx - WPOFF;
    int r = i2 / WP_C, c = i2 - r * WP_C;
    float v = 0.f;
    if (r < 100) v = Wp[r * WP_C + c];
    else if (r == 100) v = b_params[c];
    ws[idx] = v;
  }
}

__global__ __launch_bounds__(NTHR, 4) void ntm_kernel(
    const float* __restrict__ inputs, const float* __restrict__ ws,
    const float* __restrict__ W_out, const float* __restrict__ b_out,
    const int* __restrict__ seqp, float* __restrict__ outp) {
  extern __shared__ float sm[];
  const int tid = threadIdx.x;
  const int b0 = blockIdx.x * G;
  const int tlim = seqp[0] + 1;
  const int TO = T_SEQ - tlim;
  const bool buffered = (TO <= 36);
  const float* Wc = ws;
  const float* Wp = ws + WPOFF;

  // ---------------- init ----------------
  for (int i = tid; i < G * MSKT; i += NTHR) sm[OFF_M + i] = 1e-6f;
  for (int i = tid; i < 120 * 4; i += NTHR) sm[OFF_IN + i] = 0.f;
  for (int i = tid; i < 1600; i += NTHR) sm[OFF_GT + i] = 0.f;
  for (int i = tid; i < 400; i += NTHR) sm[OFF_C + i] = 0.f;
  for (int i = tid; i < 8 * 129; i += NTHR) sm[OFF_W + i] = ((i % 129) == 0) ? 1.f : 0.f;
  for (int i = tid; i < 512; i += NTHR) sm[OFF_MN + i] = 4.47213595e-6f;
  for (int i = tid; i < G * 36 * 8; i += NTHR) sm[OFF_OUT + i] = 0.f;
  for (int i = tid; i < 960; i += NTHR) sm[OFF_WO + i] = W_out[i];
  if (tid < 8) sm[OFF_BO + tid] = b_out[tid];
  if (tid >= 64 && tid < 100) {
    int p = tid - 64, g = p / 9, k = p - g * 9;
    sm[OFF_XS + k * 4 + g] = inputs[(size_t)(b0 + g) * T_SEQ * IN_DIM + k];
  }
  __syncthreads();

  // ---- prologue: gates(0) = bias + Wx*x(0)  (h0 = r0 = 0) ----
  if (tid >= 256 && tid < 456) {
    int j2 = tid - 256;
    float bA = Wc[129 * WC_C + j2], bB = Wc[129 * WC_C + j2 + 200];
    float4 pA = make_float4(bA, bA, bA, bA), pB = make_float4(bB, bB, bB, bB);
#pragma unroll
    for (int k = 0; k < IN_DIM; ++k) {
      float w0 = Wc[k * WC_C + j2], w1 = Wc[k * WC_C + j2 + 200];
      float4 x4 = *(const float4*)&sm[OFF_XS + k * 4];
      FMA4(pA, w0, x4); FMA4(pB, w1, x4);
    }
    *(float4*)&sm[OFF_GT + j2 * 4] = pA;
    *(float4*)&sm[OFF_GT + (j2 + 200) * 4] = pB;
  }
  __syncthreads();

  float4 aA = make_float4(0.f, 0.f, 0.f, 0.f), aB = aA;  // background accums

  for (int t = 0; t < T_SEQ; ++t) {
    // ---- beta: pointwise LSTM (W0-3) + x prefetch ; output(t-1) (W4-7) ----
    if (tid < 256) {
      if (tid < 200) {
        int e = tid >> 1, q = tid & 1;
        float2 gi = *(const float2*)&sm[OFF_GT + e * 4 + 2 * q];
        float2 gf = *(const float2*)&sm[OFF_GT + (100 + e) * 4 + 2 * q];
        float2 gz = *(const float2*)&sm[OFF_GT + (200 + e) * 4 + 2 * q];
        float2 go = *(const float2*)&sm[OFF_GT + (300 + e) * 4 + 2 * q];
        float2 c2 = *(const float2*)&sm[OFF_C + e * 4 + 2 * q];
        float nc0 = fsig(gf.x) * c2.x + fsig(gi.x) * ftanh(gz.x);
        float nc1 = fsig(gf.y) * c2.y + fsig(gi.y) * ftanh(gz.y);
        float h0 = fsig(go.x) * ftanh(nc0);
        float h1 = fsig(go.y) * ftanh(nc1);
        *(float2*)&sm[OFF_C + e * 4 + 2 * q] = make_float2(nc0, nc1);
        *(float2*)&sm[OFF_IN + (20 + e) * 4 + 2 * q] = make_float2(h0, h1);
      } else if (tid < 218) {
        if (t + 1 < T_SEQ) {
          int p2 = (tid - 200) * 2;
#pragma unroll
          for (int z = 0; z < 2; ++z) {
            int p = p2 + z, g = p / 9, k = p - g * 9;
            sm[OFF_XS + k * 4 + g] =
                inputs[((size_t)(b0 + g) * T_SEQ + (t + 1)) * IN_DIM + k];
          }
        }
      }
    } else if (tid < 288) {
      int s = t - 1;
      if (s >= tlim) {
        int u = tid - 256, g = u >> 3, o = u & 7;
        float v = sm[OFF_HO + g * 8 + o] + sm[OFF_BO + o];
#pragma unroll
        for (int d = 0; d < D; ++d)
          v = fmaf(sm[OFF_IN + d * 4 + g], sm[OFF_WO + (100 + d) * 8 + o], v);
        v = fminf(fmaxf(v, -CLIPV), CLIPV);
        v = fsig(v);
        int tp = s - tlim;
        if (buffered) sm[OFF_OUT + (g * TO + tp) * 8 + o] = v;
        else outp[((size_t)(b0 + g) * TO + tp) * 8 + o] = v;
      }
    }
    __syncthreads();  // B1

    // ---- gamma: p-GEMV + hout (W0-3) ; Wh rows 0-39 (W4-7) ----
    if (tid < 256) {
      if (tid < 184) {
        int j = tid >> 1, q = tid & 1;
        float bv = (q == 0) ? Wp[100 * WP_C + j] : 0.f;
        float4 acc = make_float4(bv, bv, bv, bv);
        const float* wr = Wp + (50 * q) * WP_C + j;
        const float* hb = &sm[OFF_IN + (20 + 50 * q) * 4];
#pragma unroll 5
        for (int i = 0; i < 50; ++i) {
          float w0 = wr[i * WP_C];
          float4 h4 = *(const float4*)(hb + i * 4);
          FMA4(acc, w0, h4);
        }
        acc.x = pred(acc.x); acc.y = pred(acc.y);
        acc.z = pred(acc.z); acc.w = pred(acc.w);
        if (q == 0) {
          acc.x = fminf(fmaxf(acc.x, -CLIPV), CLIPV);
          acc.y = fminf(fmaxf(acc.y, -CLIPV), CLIPV);
          acc.z = fminf(fmaxf(acc.z, -CLIPV), CLIPV);
          acc.w = fminf(fmaxf(acc.w, -CLIPV), CLIPV);
          *(float4*)&sm[OFF_P + j * 4] = acc;
        }
      } else if (tid >= 192) {
        int u2 = tid - 192, g = u2 >> 4, o = (u2 >> 1) & 7, hf = u2 & 1;
        const float* hb = &sm[OFF_IN + (20 + 50 * hf) * 4 + g];
        const float* wo = &sm[OFF_WO + (50 * hf) * 8 + o];
        float s = 0.f;
#pragma unroll 10
        for (int k = 0; k < 50; ++k) s = fmaf(hb[k * 4], wo[k * 8], s);
        s = pred(s);
        if (hf == 0) sm[OFF_HO + g * 8 + o] = s;
      }
    } else {
      int j2 = tid - 256;
      if (j2 < 200) {
        float bA = Wc[129 * WC_C + j2], bB = Wc[129 * WC_C + j2 + 200];
        aA = make_float4(bA, bA, bA, bA);
        aB = make_float4(bB, bB, bB, bB);
        const float* wr = Wc + 29 * WC_C + j2;
        const float* hb = &sm[OFF_IN + 20 * 4];
#pragma unroll 8
        for (int i = 0; i < 40; ++i) {
          float w0 = wr[i * WC_C], w1 = wr[i * WC_C + 200];
          float4 h4 = *(const float4*)(hb + i * 4);
          FMA4(aA, w0, h4); FMA4(aB, w1, h4);
        }
      }
    }
    __syncthreads();  // B2

    // ---- delta: addressing, wave w -> g=w, both heads (W0-3) ; Wh rows 40-79 (W4-7) ----
    if (tid < 256) {
      const int g = tid >> 6, l = tid & 63;
      if (l < 40) {
        int hd = l >= 20, j = l - 20 * hd;
        sm[OFF_KV + (2 * g + hd) * 20 + j] = ftanh(sm[OFF_P + (hd * 26 + j) * 4 + g]);
      } else if (l < 52) {
        int hd = (l - 40) >= 6, which = (l - 40) - 6 * hd;
        float v = sm[OFF_P + (hd * 26 + 20 + which) * 4 + g];
        float* scp = &sm[OFF_SC + (2 * g + hd) * 8];
        if (which == 0) scp[0] = fsoftplus(v);
        else if (which == 1) scp[1] = fsig(v);
        else if (which == 2) {
          float a1 = sm[OFF_P + (hd * 26 + 23) * 4 + g];
          float a2 = sm[OFF_P + (hd * 26 + 24) * 4 + g];
          float mx = fmaxf(v, fmaxf(a1, a2));
          float e0 = fexp(v - mx), e1 = fexp(a1 - mx), e2 = fexp(a2 - mx);
          float inv = frcp(e0 + e1 + e2);
          scp[2] = e0 * inv; scp[3] = e1 * inv; scp[4] = e2 * inv;
        } else if (which == 5) {
          scp[5] = fsoftplus(v) + 1.f;
        }
      }
      asm volatile("s_waitcnt lgkmcnt(0)" ::: "memory");  // wave-internal publish

      const float* Mg = &sm[OFF_M + g * MSKT];
      const float* kv0 = &sm[OFF_KV + (2 * g) * 20];
      const float* kv1 = &sm[OFF_KV + (2 * g + 1) * 20];
      float d00 = 0.f, d01 = 0.f, d10 = 0.f, d11 = 0.f, kn0 = 0.f, kn1 = 0.f;
#pragma unroll
      for (int d = 0; d < D; ++d) {
        float k0 = kv0[d], k1 = kv1[d];
        float m0 = Mg[d * MT_ROW + l], m1 = Mg[d * MT_ROW + 64 + l];
        d00 = fmaf(k0, m0, d00); d01 = fmaf(k0, m1, d01);
        d10 = fmaf(k1, m0, d10); d11 = fmaf(k1, m1, d11);
        kn0 = fmaf(k0, k0, kn0); kn1 = fmaf(k1, k1, kn1);
      }
      kn0 = sqrtf(kn0); kn1 = sqrtf(kn1);
      float Mn0 = sm[OFF_MN + g * 128 + l], Mn1 = sm[OFF_MN + g * 128 + 64 + l];
      const float* sc0 = &sm[OFF_SC + (2 * g) * 8];
      const float* sc1 = &sm[OFF_SC + (2 * g + 1) * 8];
      float be0 = sc0[0], be1 = sc1[0];
      float S00 = be0 * d00 * frcp(kn0 * Mn0 + 1e-8f);
      float S01 = be0 * d01 * frcp(kn0 * Mn1 + 1e-8f);
      float S10 = be1 * d10 * frcp(kn1 * Mn0 + 1e-8f);
      float S11 = be1 * d11 * frcp(kn1 * Mn1 + 1e-8f);
      float mx0 = fmaxf(S00, S01), mx1 = fmaxf(S10, S11);
      wred_max2(mx0, mx1);
      float e00 = fexp(S00 - mx0), e01 = fexp(S01 - mx0);
      float e10 = fexp(S10 - mx1), e11 = fexp(S11 - mx1);
      float sum0 = e00 + e01, sum1 = e10 + e11;
      wred_sum2(sum0, sum1);
      float si0 = frcp(sum0), si1 = frcp(sum1);
      float* wpa = &sm[OFF_W + (2 * g) * 129];
      float* wpb = &sm[OFF_W + (2 * g + 1) * 129];
      float gg0 = sc0[1], gg1 = sc1[1];
      float wa0 = wpa[l], wa1 = wpa[64 + l], wb0 = wpb[l], wb1 = wpb[64 + l];
      float wg00 = fmaf(gg0, e00 * si0 - wa0, wa0);
      float wg01 = fmaf(gg0, e01 * si0 - wa1, wa1);
      float wg10 = fmaf(gg1, e10 * si1 - wb0, wb0);
      float wg11 = fmaf(gg1, e11 * si1 - wb1, wb1);
      int lp = (l + 1) & 63, lm = (l + 63) & 63;
      // head0 shift
      float n00 = __shfl(wg00, lp, 64), n01 = __shfl(wg01, lp, 64);
      float p00 = __shfl(wg00, lm, 64), p01 = __shfl(wg01, lm, 64);
      float a0l0 = __shfl(wg00, 0, 64), a1l0 = __shfl(wg01, 0, 64);
      float a0l63 = __shfl(wg00, 63, 64), a1l63 = __shfl(wg01, 63, 64);
      float nxt00 = (l == 63) ? a1l0 : n00;
      float nxt01 = (l == 63) ? a0l0 : n01;
      float prv00 = (l == 0) ? a1l63 : p00;
      float prv01 = (l == 0) ? a0l63 : p01;
      // head1 shift
      float n10 = __shfl(wg10, lp, 64), n11 = __shfl(wg11, lp, 64);
      float p10 = __shfl(wg10, lm, 64), p11 = __shfl(wg11, lm, 64);
      float b0l0 = __shfl(wg10, 0, 64), b1l0 = __shfl(wg11, 0, 64);
      float b0l63 = __shfl(wg10, 63, 64), b1l63 = __shfl(wg11, 63, 64);
      float nxt10 = (l == 63) ? b1l0 : n10;
      float nxt11 = (l == 63) ? b0l0 : n11;
      float prv10 = (l == 0) ? b1l63 : p10;
      float prv11 = (l == 0) ? b0l63 : p11;
      float s00 = sc0[2], s01s = sc0[3], s02 = sc0[4], gm0 = sc0[5];
      float s10 = sc1[2], s11s = sc1[3], s12 = sc1[4], gm1 = sc1[5];
      float wt00 = fmaxf(fmaf(s00, nxt00, fmaf(s01s, wg00, s02 * prv00)), 1e-16f);
      float wt01 = fmaxf(fmaf(s00, nxt01, fmaf(s01s, wg01, s02 * prv01)), 1e-16f);
      float wt10 = fmaxf(fmaf(s10, nxt10, fmaf(s11s, wg10, s12 * prv10)), 1e-16f);
      float wt11 = fmaxf(fmaf(s10, nxt11, fmaf(s11s, wg11, s12 * prv11)), 1e-16f);
      float m0m = fmaxf(wt00, wt01), m1m = fmaxf(wt10, wt11);
      wred_max2(m0m, m1m);
      float iv0 = frcp(m0m), iv1 = frcp(m1m);
      float q00 = fexp2(gm0 * flog2(wt00 * iv0));
      float q01 = fexp2(gm0 * flog2(wt01 * iv0));
      float q10 = fexp2(gm1 * flog2(wt10 * iv1));
      float q11 = fexp2(gm1 * flog2(wt11 * iv1));
      float sq0 = q00 + q01, sq1 = q10 + q11;
      wred_sum2(sq0, sq1);
      float pi0 = frcp(sq0), pi1 = frcp(sq1);
      wpa[l] = q00 * pi0; wpa[64 + l] = q01 * pi0;
      wpb[l] = q10 * pi1; wpb[64 + l] = q11 * pi1;
    } else {
      int j2 = tid - 256;
      if (j2 < 200) {
        const float* wr = Wc + 69 * WC_C + j2;
        const float* hb = &sm[OFF_IN + 60 * 4];
#pragma unroll 8
        for (int i = 0; i < 40; ++i) {
          float w0 = wr[i * WC_C], w1 = wr[i * WC_C + 200];
          float4 h4 = *(const float4*)(hb + i * 4);
          FMA4(aA, w0, h4); FMA4(aB, w1, h4);
        }
      }
    }
    __syncthreads();  // B3

    // ---- eps: r = w_r @ M, e/a (W0-3) ; Wh rows 80-99 (W4-7) ----
    if (tid < 256) {
      if (tid < 160) {
        int pr = tid >> 1, nq = tid & 1;
        int g = pr / 20, d = pr - g * 20;
        const float* wr = &sm[OFF_W + (2 * g) * 129];
        const float* Md = &sm[OFF_M + g * MSKT + d * MT_ROW];
        float s = 0.f;
#pragma unroll 8
        for (int i = 0; i < 64; ++i) {
          int n = nq + 2 * i;
          s = fmaf(wr[n], Md[n], s);
        }
        s = pred(s);
        if (nq == 0) sm[OFF_IN + d * 4 + g] = s;
      } else if (tid < 240) {
        int p = tid - 160, g = p / 20, jj = (p - g * 20) * 2;
#pragma unroll
        for (int z = 0; z < 2; ++z) {
          int j = jj + z;
          float v = sm[OFF_P + (52 + j) * 4 + g];
          sm[OFF_EA + g * 40 + j] = (j < 20) ? fsig(v) : ftanh(v);
        }
      }
    } else {
      int j2 = tid - 256;
      if (j2 < 200) {
        const float* wr = Wc + 109 * WC_C + j2;
        const float* hb = &sm[OFF_IN + 100 * 4];
#pragma unroll 5
        for (int i = 0; i < 20; ++i) {
          float w0 = wr[i * WC_C], w1 = wr[i * WC_C + 200];
          float4 h4 = *(const float4*)(hb + i * 4);
          FMA4(aA, w0, h4); FMA4(aB, w1, h4);
        }
      }
    }
    __syncthreads();  // B4

    // ---- zeta: M update + norm (W0-3) ; x/r gates rows + publish (W4-7) ----
    if (tid < 256) {
      int g = tid >> 6, n0 = tid & 63;
      const float* ep = &sm[OFF_EA + g * 40];
      const float* ap = ep + 20;
      float* Mg = &sm[OFF_M + g * MSKT];
#pragma unroll
      for (int h2 = 0; h2 < 2; ++h2) {
        int n = n0 + 64 * h2;
        float ww = sm[OFF_W + (2 * g + 1) * 129 + n];
        float nrm = 0.f;
#pragma unroll
        for (int d = 0; d < D; ++d) {
          float mv = Mg[d * MT_ROW + n];
          mv = fmaf(ww, fmaf(-ep[d], mv, ap[d]), mv);
          Mg[d * MT_ROW + n] = mv;
          nrm = fmaf(mv, mv, nrm);
        }
        sm[OFF_MN + g * 128 + n] = sqrtf(nrm);
      }
    } else {
      int j2 = tid - 256;
      if (j2 < 200) {
        const float* wrx = Wc + j2;
#pragma unroll
        for (int k = 0; k < IN_DIM; ++k) {
          float w0 = wrx[k * WC_C], w1 = wrx[k * WC_C + 200];
          float4 x4 = *(const float4*)&sm[OFF_XS + k * 4];
          FMA4(aA, w0, x4); FMA4(aB, w1, x4);
        }
        const float* wrr = Wc + 9 * WC_C + j2;
#pragma unroll 5
        for (int k = 0; k < 20; ++k) {
          float w0 = wrr[k * WC_C], w1 = wrr[k * WC_C + 200];
          float4 r4 = *(const float4*)&sm[OFF_IN + k * 4];
          FMA4(aA, w0, r4); FMA4(aB, w1, r4);
        }
        *(float4*)&sm[OFF_GT + j2 * 4] = aA;
        *(float4*)&sm[OFF_GT + (j2 + 200) * 4] = aB;
      }
    }
    __syncthreads();  // B5
  }

  // ---- epilogue: output for t = T_SEQ-1, then flush ----
  if (tid < 32) {
    int s = T_SEQ - 1;
    if (s >= tlim) {
      int g = tid >> 3, o = tid & 7;
      float v = sm[OFF_HO + g * 8 + o] + sm[OFF_BO + o];
#pragma unroll
      for (int d = 0; d < D; ++d)
        v = fmaf(sm[OFF_IN + d * 4 + g], sm[OFF_WO + (100 + d) * 8 + o], v);
      v = fminf(fmaxf(v, -CLIPV), CLIPV);
      v = fsig(v);
      int tp = s - tlim;
      if (buffered) sm[OFF_OUT + (g * TO + tp) * 8 + o] = v;
      else outp[((size_t)(b0 + g) * TO + tp) * 8 + o] = v;
    }
  }
  __syncthreads();
  if (buffered) {
    const int total = G * TO * 8;
    for (int i = tid * 4; i < total; i += NTHR * 4) {
      float4 v = *(const float4*)&sm[OFF_OUT + i];
      *(float4*)&outp[(size_t)blockIdx.x * total + i] = v;
    }
  }
}

}  // namespace

extern "C" void kernel_launch(void* const* d_in, const int* in_sizes, int n_in,
                              void* d_out, int out_size, void* d_ws, size_t ws_size,
                              hipStream_t stream) {
  (void)in_sizes; (void)n_in; (void)out_size; (void)ws_size;
  const float* inputs   = (const float*)d_in[0];
  const float* Wx       = (const float*)d_in[1];
  const float* Wh       = (const float*)d_in[2];
  const float* b_lstm   = (const float*)d_in[3];
  const float* W_params = (const float*)d_in[4];
  const float* b_params = (const float*)d_in[5];
  const float* W_out    = (const float*)d_in[6];
  const float* b_out    = (const float*)d_in[7];
  const int*   seqp     = (const int*)d_in[8];
  float* out = (float*)d_out;
  float* ws  = (float*)d_ws;

  constexpr int SETUP_N = WC_R * WC_C + WP_R * WP_C;
  setup_kernel<<<(SETUP_N + 255) / 256, 256, 0, stream>>>(ws, Wx, Wh, b_lstm,
                                                          W_params, b_params);

  hipFuncSetAttribute((const void*)ntm_kernel,
                      hipFuncAttributeMaxDynamicSharedMemorySize, SMEM_BYTES);
  ntm_kernel<<<B_TOT / G, NTHR, SMEM_BYTES, stream>>>(inputs, ws, W_out, b_out,
                                                      seqp, out);
}

// Round 5
// 963.764 us; speedup vs baseline: 3.9045x; 1.1882x over previous
//
#include <hip/hip_runtime.h>

namespace {

constexpr int B_TOT  = 2048;
constexpr int T_SEQ  = 66;
constexpr int IN_DIM = 9;
constexpr int H      = 100;
constexpr int N      = 128;
constexpr int D      = 20;
constexpr int G      = 4;      // sequences per block
constexpr int NTHR   = 512;    // 8 waves
constexpr float CLIPV = 20.0f;

// fragment geometry (16x16x32 bf16 MFMA)
constexpr int NCT_BIG = 32;    // 32 col-tiles x16 = 512 cols: 0-399 gates, 400-491 p, 492-499 hout
constexpr int NKT_BIG = 4;     // 4 k-tiles x32 = 128 (100 used)
constexpr int NCT_SM  = 25;    // small GEMM: gates cols only, K=32 (x 9 + r 20)
constexpr int WS_BIG_SLOTS = NCT_BIG * NKT_BIG * 64;   // 8192 lane-slots x 8 bf16
constexpr int WS_SM_OFF_U16 = WS_BIG_SLOTS * 8;        // 65536 ushorts
constexpr int WS_SM_SLOTS = NCT_SM * 64;               // 1600

constexpr int MT_ROW = 132;             // M transposed [d][n], n padded to 132
constexpr int MSKT   = D * MT_ROW + 4;  // 2644 per-g stride

// ---- LDS layout (float words) ----
constexpr int OFF_M    = 0;                    // [4][20][132]
constexpr int OFF_GT   = OFF_M + G * MSKT;     // [512][4]: 0-399 gates, 400-491 p, 492-499 hout
constexpr int OFF_C    = OFF_GT + 2048;        // [100][4]
constexpr int OFF_HA   = OFF_C + 400;          // ushort[2][4][128] h hi/lo
constexpr int OFF_SA   = OFF_HA + 512;         // ushort[4][32]  [x(9) r(20) pad]
constexpr int OFF_BIAS = OFF_SA + 64;          // [512]
constexpr int OFF_R    = OFF_BIAS + 512;       // [20][4] fp32 r
constexpr int OFF_KV   = OFF_R + 80;           // [8][20]
constexpr int OFF_SC   = OFF_KV + 160;         // [8][8]
constexpr int OFF_EA   = OFF_SC + 64;          // [4][40]
constexpr int OFF_MN   = OFF_EA + 160;         // [4][128]
constexpr int OFF_W    = OFF_MN + 512;         // [8][129]
constexpr int OFF_WO2  = OFF_W + 1032;         // [20][8] W_out rows 100-119
constexpr int OFF_OUT  = OFF_WO2 + 160;        // [4*36*8]
constexpr int SMEM_FLOATS = OFF_OUT + 1152;    // 17432
constexpr int SMEM_BYTES  = SMEM_FLOATS * 4;   // 69728 -> 2 blocks/CU

typedef __attribute__((ext_vector_type(8))) short bf16x8;
typedef __attribute__((ext_vector_type(4))) float f32x4;

__device__ __forceinline__ float fexp2(float x) { return __builtin_amdgcn_exp2f(x); }
__device__ __forceinline__ float flog2(float x) { return __builtin_amdgcn_logf(x); }
__device__ __forceinline__ float frcp(float x)  { return __builtin_amdgcn_rcpf(x); }
__device__ __forceinline__ float fexp(float x)  { return fexp2(x * 1.4426950408889634f); }
__device__ __forceinline__ float fsig(float x)  { return frcp(1.f + fexp2(-1.4426950408889634f * x)); }
__device__ __forceinline__ float ftanh(float x) { return 1.f - 2.f * frcp(1.f + fexp2(2.8853900817779268f * x)); }
__device__ __forceinline__ float fsoftplus(float x) { return log1pf(fexp(x)); }

__device__ __forceinline__ unsigned short f2bf(float x) {
  unsigned u = __float_as_uint(x);
  u = (u + 0x7FFFu + ((u >> 16) & 1u)) >> 16;
  return (unsigned short)u;
}
__device__ __forceinline__ float bf2f(unsigned short h) {
  return __uint_as_float(((unsigned)h) << 16);
}

template <int C>
__device__ __forceinline__ float dpp_add(float x) {
  return x + __int_as_float(__builtin_amdgcn_mov_dpp(__float_as_int(x), C, 0xF, 0xF, true));
}
__device__ __forceinline__ float qred(float x) { return dpp_add<0x4E>(dpp_add<0xB1>(x)); }

__device__ __forceinline__ float wred_max(float v) {
#pragma unroll
  for (int off = 32; off; off >>= 1) v = fmaxf(v, __shfl_xor(v, off, 64));
  return v;
}
__device__ __forceinline__ float wred_sum(float v) {
#pragma unroll
  for (int off = 32; off; off >>= 1) v += __shfl_xor(v, off, 64);
  return v;
}

// ---- setup: pre-swizzle weights into MFMA B-fragment layout (bf16) ----
// big: slot = (ct*4+kt)*64+lane; lane holds col=ct*16+(lane&15), k=kt*32+(lane>>4)*8+j
// cols: <400 Wh[k][col]; <492 Wp[k][col-400]; <500 W_out[k][col-492]; k>=100 -> 0
// small: slot2 = ct*64+lane; k=(lane>>4)*8+j; k<29 -> Wx[k][col] (ctrl=[x,r]); else 0
__global__ void setup_kernel(unsigned short* __restrict__ ws,
                             const float* __restrict__ Wx, const float* __restrict__ Wh,
                             const float* __restrict__ Wp, const float* __restrict__ Wo) {
  int idx = blockIdx.x * 256 + threadIdx.x;
  if (idx < WS_BIG_SLOTS) {
    int lane = idx & 63, kt = (idx >> 6) & 3, ct = idx >> 8;
    int col = ct * 16 + (lane & 15);
    int k0 = kt * 32 + ((lane >> 4) << 3);
    unsigned short v[8];
#pragma unroll
    for (int j = 0; j < 8; ++j) {
      int k = k0 + j;
      float f = 0.f;
      if (k < 100) {
        if (col < 400) f = Wh[k * 400 + col];
        else if (col < 492) f = Wp[k * 92 + (col - 400)];
        else if (col < 500) f = Wo[k * 8 + (col - 492)];
      }
      v[j] = f2bf(f);
    }
    uint4 pk;
    pk.x = (unsigned)v[0] | ((unsigned)v[1] << 16);
    pk.y = (unsigned)v[2] | ((unsigned)v[3] << 16);
    pk.z = (unsigned)v[4] | ((unsigned)v[5] << 16);
    pk.w = (unsigned)v[6] | ((unsigned)v[7] << 16);
    *(uint4*)(ws + (size_t)idx * 8) = pk;
  } else if (idx < WS_BIG_SLOTS + WS_SM_SLOTS) {
    int s = idx - WS_BIG_SLOTS;
    int lane = s & 63, ct = s >> 6;
    int col = ct * 16 + (lane & 15);
    int k0 = (lane >> 4) << 3;
    unsigned short v[8];
#pragma unroll
    for (int j = 0; j < 8; ++j) {
      int k = k0 + j;
      float f = (k < 29) ? Wx[k * 400 + col] : 0.f;
      v[j] = f2bf(f);
    }
    uint4 pk;
    pk.x = (unsigned)v[0] | ((unsigned)v[1] << 16);
    pk.y = (unsigned)v[2] | ((unsigned)v[3] << 16);
    pk.z = (unsigned)v[4] | ((unsigned)v[5] << 16);
    pk.w = (unsigned)v[6] | ((unsigned)v[7] << 16);
    *(uint4*)(ws + (size_t)(WS_SM_OFF_U16 + (size_t)s * 8)) = pk;
  }
}

__global__ __launch_bounds__(NTHR, 4) void ntm_kernel(
    const float* __restrict__ inputs, const unsigned short* __restrict__ wsu,
    const float* __restrict__ b_lstm, const float* __restrict__ b_params,
    const float* __restrict__ b_out, const float* __restrict__ W_out,
    const int* __restrict__ seqp, float* __restrict__ outp) {
  extern __shared__ float sm[];
  const int tid = threadIdx.x;
  const int lane = tid & 63;
  const int wv = tid >> 6;
  const int b0 = blockIdx.x * G;
  const int tlim = seqp[0] + 1;
  const int TO = T_SEQ - tlim;
  const bool buffered = (TO <= 36);
  unsigned short* hAu = (unsigned short*)(sm + OFF_HA);
  unsigned short* sAu = (unsigned short*)(sm + OFF_SA);
  const bf16x8* wsBig = (const bf16x8*)wsu;
  const bf16x8* wsSm  = (const bf16x8*)(wsu + WS_SM_OFF_U16);

  // ---------------- init ----------------
  for (int i = tid; i < G * MSKT; i += NTHR) sm[OFF_M + i] = 1e-6f;
  for (int i = tid; i < 2048; i += NTHR) sm[OFF_GT + i] = 0.f;
  for (int i = tid; i < 400; i += NTHR) sm[OFF_C + i] = 0.f;
  for (int i = tid; i < 1024; i += NTHR) hAu[i] = 0;
  for (int i = tid; i < 128; i += NTHR) sAu[i] = 0;
  if (tid < 512) {
    float v = 0.f;
    if (tid < 400) v = b_lstm[tid];
    else if (tid < 492) v = b_params[tid - 400];
    else if (tid < 500) v = b_out[tid - 492];
    sm[OFF_BIAS + tid] = v;
  }
  for (int i = tid; i < 80; i += NTHR) sm[OFF_R + i] = 0.f;
  for (int i = tid; i < 512; i += NTHR) sm[OFF_MN + i] = 4.47213595e-6f;
  for (int i = tid; i < 1032; i += NTHR) sm[OFF_W + i] = ((i % 129) == 0) ? 1.f : 0.f;
  for (int i = tid; i < 160; i += NTHR) sm[OFF_WO2 + i] = W_out[800 + i];
  for (int i = tid; i < 1152; i += NTHR) sm[OFF_OUT + i] = 0.f;
  __syncthreads();
  if (tid < 36) {  // x(0)
    int g = tid / 9, k = tid - g * 9;
    sAu[g * 32 + k] = f2bf(inputs[(size_t)(b0 + g) * T_SEQ * IN_DIM + k]);
  }
  __syncthreads();

  const int ct0 = wv * 4;
  const int arow = lane & 3;
  const int akoff = (lane >> 4) << 3;
  f32x4 acc[4];

  // ---- prologue: gates(0) = bias + [x(0), 0] @ Wx ----
  {
    bf16x8 as = *(const bf16x8*)(sAu + arow * 32 + akoff);
#pragma unroll
    for (int cti = 0; cti < 4; ++cti) {
      int ct = ct0 + cti;
      if (ct < NCT_SM) {
        float bv = sm[OFF_BIAS + ct * 16 + (lane & 15)];
        f32x4 a = {bv, bv, bv, bv};
        bf16x8 bs = wsSm[ct * 64 + lane];
        a = __builtin_amdgcn_mfma_f32_16x16x32_bf16(as, bs, a, 0, 0, 0);
        if (lane < 16) *(f32x4*)&sm[OFF_GT + (ct * 16 + lane) * 4] = a;
      }
    }
  }
  __syncthreads();

  for (int t = 0; t < T_SEQ; ++t) {
    // ---- P_A: pointwise LSTM -> h hi/lo bf16 ; x prefetch ; output(t-1) ----
    if (tid < 400) {
      int e = tid >> 2, g = tid & 3;
      float gi = sm[OFF_GT + e * 4 + g];
      float gf = sm[OFF_GT + (100 + e) * 4 + g];
      float gz = sm[OFF_GT + (200 + e) * 4 + g];
      float go = sm[OFF_GT + (300 + e) * 4 + g];
      float c = sm[OFF_C + e * 4 + g];
      float nc = fsig(gf) * c + fsig(gi) * ftanh(gz);
      float h = fsig(go) * ftanh(nc);
      sm[OFF_C + e * 4 + g] = nc;
      unsigned short hh = f2bf(h);
      unsigned short hl = f2bf(h - bf2f(hh));
      hAu[g * 128 + e] = hh;
      hAu[512 + g * 128 + e] = hl;
    } else if (tid >= 416 && tid < 452) {
      if (t + 1 < T_SEQ) {
        int p = tid - 416, g = p / 9, k = p - g * 9;
        sAu[g * 32 + k] =
            f2bf(inputs[((size_t)(b0 + g) * T_SEQ + (t + 1)) * IN_DIM + k]);
      }
    } else if (tid >= 456 && tid < 488) {
      int s = t - 1;
      if (s >= tlim) {
        int u = tid - 456, g = u >> 3, o = u & 7;
        float v = sm[OFF_GT + (492 + o) * 4 + g];
#pragma unroll
        for (int d = 0; d < D; ++d)
          v = fmaf(sm[OFF_R + d * 4 + g], sm[OFF_WO2 + d * 8 + o], v);
        v = fminf(fmaxf(v, -CLIPV), CLIPV);
        v = fsig(v);
        int tp = s - tlim;
        if (buffered) sm[OFF_OUT + (g * TO + tp) * 8 + o] = v;
        else outp[((size_t)(b0 + g) * TO + tp) * 8 + o] = v;
      }
    }
    __syncthreads();  // B1

    // ---- P_B: big GEMM h(t) @ [Wh|Wp|Wout]: 2 passes (h_hi, h_lo) share B ----
    {
      bf16x8 ahi[4], alo[4];
#pragma unroll
      for (int kt = 0; kt < 4; ++kt) {
        ahi[kt] = *(const bf16x8*)(hAu + arow * 128 + kt * 32 + akoff);
        alo[kt] = *(const bf16x8*)(hAu + 512 + arow * 128 + kt * 32 + akoff);
      }
#pragma unroll
      for (int cti = 0; cti < 4; ++cti) {
        int ct = ct0 + cti;
        int colb = ct * 16;
        float bv = sm[OFF_BIAS + colb + (lane & 15)];
        f32x4 a = {bv, bv, bv, bv};
#pragma unroll
        for (int kt = 0; kt < 4; ++kt) {
          bf16x8 bf = wsBig[(ct * 4 + kt) * 64 + lane];
          a = __builtin_amdgcn_mfma_f32_16x16x32_bf16(ahi[kt], bf, a, 0, 0, 0);
          a = __builtin_amdgcn_mfma_f32_16x16x32_bf16(alo[kt], bf, a, 0, 0, 0);
        }
        acc[cti] = a;
        if (colb >= 400 && lane < 16) {
          int col = colb + lane;
          if (col < 500) {
            f32x4 v = a;
            if (col < 492) {  // p: clip
              v.x = fminf(fmaxf(v.x, -CLIPV), CLIPV);
              v.y = fminf(fmaxf(v.y, -CLIPV), CLIPV);
              v.z = fminf(fmaxf(v.z, -CLIPV), CLIPV);
              v.w = fminf(fmaxf(v.w, -CLIPV), CLIPV);
            }
            *(f32x4*)&sm[OFF_GT + col * 4] = v;
          }
        }
      }
    }
    __syncthreads();  // B2

    // ---- P_C: addressing, one (g,head) per wave ----
    {
      const int g = wv & 3, hd = wv >> 2, gh = 2 * g + hd;
      const int l = lane;
      if (l < 20) {
        sm[OFF_KV + gh * 20 + l] = ftanh(sm[OFF_GT + (400 + hd * 26 + l) * 4 + g]);
      } else if (l < 26) {
        int which = l - 20;
        float v = sm[OFF_GT + (400 + hd * 26 + 20 + which) * 4 + g];
        float* scp = &sm[OFF_SC + gh * 8];
        if (which == 0) scp[0] = fsoftplus(v);
        else if (which == 1) scp[1] = fsig(v);
        else if (which == 2) {
          float a1 = sm[OFF_GT + (400 + hd * 26 + 23) * 4 + g];
          float a2 = sm[OFF_GT + (400 + hd * 26 + 24) * 4 + g];
          float mx = fmaxf(v, fmaxf(a1, a2));
          float e0 = fexp(v - mx), e1 = fexp(a1 - mx), e2 = fexp(a2 - mx);
          float inv = frcp(e0 + e1 + e2);
          scp[2] = e0 * inv; scp[3] = e1 * inv; scp[4] = e2 * inv;
        } else if (which == 5) {
          scp[5] = fsoftplus(v) + 1.f;
        }
      }
      asm volatile("s_waitcnt lgkmcnt(0)" ::: "memory");
      __builtin_amdgcn_sched_barrier(0);

      const float* Mg = &sm[OFF_M + g * MSKT];
      const float* kvp = &sm[OFF_KV + gh * 20];
      float kn = 0.f, d0 = 0.f, d1 = 0.f;
#pragma unroll
      for (int d = 0; d < D; ++d) {
        float kd = kvp[d];
        float m0 = Mg[d * MT_ROW + l], m1 = Mg[d * MT_ROW + 64 + l];
        kn = fmaf(kd, kd, kn);
        d0 = fmaf(kd, m0, d0);
        d1 = fmaf(kd, m1, d1);
      }
      kn = sqrtf(kn);
      float Mn0 = sm[OFF_MN + g * 128 + l], Mn1 = sm[OFF_MN + g * 128 + 64 + l];
      const float* scp = &sm[OFF_SC + gh * 8];
      float beta = scp[0], gg = scp[1], s0 = scp[2], s1 = scp[3], s2 = scp[4];
      float gamma = scp[5];
      float S0 = beta * d0 * frcp(kn * Mn0 + 1e-8f);
      float S1 = beta * d1 * frcp(kn * Mn1 + 1e-8f);
      float mx = wred_max(fmaxf(S0, S1));
      float e0 = fexp(S0 - mx), e1 = fexp(S1 - mx);
      float sinv = frcp(wred_sum(e0 + e1));
      float* wp = &sm[OFF_W + gh * 129];
      float wp0 = wp[l], wp1 = wp[64 + l];
      float wg0 = fmaf(gg, e0 * sinv - wp0, wp0);
      float wg1 = fmaf(gg, e1 * sinv - wp1, wp1);
      int lp = (l + 1) & 63, lm = (l + 63) & 63;
      float n0a = __shfl(wg0, lp, 64), n1a = __shfl(wg1, lp, 64);
      float p0a = __shfl(wg0, lm, 64), p1a = __shfl(wg1, lm, 64);
      float w1l0 = __shfl(wg1, 0, 64), w0l0 = __shfl(wg0, 0, 64);
      float w0l63 = __shfl(wg0, 63, 64), w1l63 = __shfl(wg1, 63, 64);
      float nxt0 = (l == 63) ? w1l0 : n0a;
      float nxt1 = (l == 63) ? w0l0 : n1a;
      float prv0 = (l == 0) ? w1l63 : p0a;
      float prv1 = (l == 0) ? w0l63 : p1a;
      float wt0 = fmaxf(fmaf(s0, nxt0, fmaf(s1, wg0, s2 * prv0)), 1e-16f);
      float wt1 = fmaxf(fmaf(s0, nxt1, fmaf(s1, wg1, s2 * prv1)), 1e-16f);
      float invm = frcp(wred_max(fmaxf(wt0, wt1)));
      float q0 = fexp2(gamma * flog2(wt0 * invm));
      float q1 = fexp2(gamma * flog2(wt1 * invm));
      float pinv = frcp(wred_sum(q0 + q1));
      wp[l] = q0 * pinv;
      wp[64 + l] = q1 * pinv;
    }
    __syncthreads();  // B3

    // ---- P_D: r = w_r @ M (fp32 + bf16 into small-A) ; e/a activations ----
    if (tid < 320) {
      int pr = tid >> 2, nq = tid & 3;
      int g = pr / 20, d = pr - g * 20;
      const float* wr = &sm[OFF_W + (2 * g) * 129];
      const float* Md = &sm[OFF_M + g * MSKT + d * MT_ROW];
      float s = 0.f;
#pragma unroll 8
      for (int i = 0; i < 32; ++i) {
        int n = nq + 4 * i;
        s = fmaf(wr[n], Md[n], s);
      }
      s = qred(s);
      if (nq == 0) {
        sm[OFF_R + d * 4 + g] = s;
        sAu[g * 32 + 9 + d] = f2bf(s);
      }
    } else if (tid < 480) {
      int p = tid - 320, g = p / 40, j = p - g * 40;
      float v = sm[OFF_GT + (452 + j) * 4 + g];
      sm[OFF_EA + g * 40 + j] = (j < 20) ? fsig(v) : ftanh(v);
    }
    __syncthreads();  // B4

    // ---- P_E: small GEMM [x(t+1),r(t)] @ Wx -> gates(t+1) ; M update + norm ----
    {
      bf16x8 as = *(const bf16x8*)(sAu + arow * 32 + akoff);
#pragma unroll
      for (int cti = 0; cti < 4; ++cti) {
        int ct = ct0 + cti;
        if (ct < NCT_SM) {
          bf16x8 bs = wsSm[ct * 64 + lane];
          acc[cti] = __builtin_amdgcn_mfma_f32_16x16x32_bf16(as, bs, acc[cti], 0, 0, 0);
          if (lane < 16) *(f32x4*)&sm[OFF_GT + (ct * 16 + lane) * 4] = acc[cti];
        }
      }
    }
    if (tid < 256) {
      int g = tid >> 6, n0 = tid & 63;
      const float* ep = &sm[OFF_EA + g * 40];
      const float* ap = ep + 20;
      float* Mg = &sm[OFF_M + g * MSKT];
#pragma unroll
      for (int h2 = 0; h2 < 2; ++h2) {
        int n = n0 + 64 * h2;
        float ww = sm[OFF_W + (2 * g + 1) * 129 + n];
        float nrm = 0.f;
#pragma unroll
        for (int d = 0; d < D; ++d) {
          float mv = Mg[d * MT_ROW + n];
          mv = fmaf(ww, fmaf(-ep[d], mv, ap[d]), mv);
          Mg[d * MT_ROW + n] = mv;
          nrm = fmaf(mv, mv, nrm);
        }
        sm[OFF_MN + g * 128 + n] = sqrtf(nrm);
      }
    }
    __syncthreads();  // B5
  }

  // ---- epilogue: output for t = T_SEQ-1, then flush ----
  if (tid < 32) {
    int s = T_SEQ - 1;
    if (s >= tlim) {
      int g = tid >> 3, o = tid & 7;
      float v = sm[OFF_GT + (492 + o) * 4 + g];
#pragma unroll
      for (int d = 0; d < D; ++d)
        v = fmaf(sm[OFF_R + d * 4 + g], sm[OFF_WO2 + d * 8 + o], v);
      v = fminf(fmaxf(v, -CLIPV), CLIPV);
      v = fsig(v);
      int tp = s - tlim;
      if (buffered) sm[OFF_OUT + (g * TO + tp) * 8 + o] = v;
      else outp[((size_t)(b0 + g) * TO + tp) * 8 + o] = v;
    }
  }
  __syncthreads();
  if (buffered) {
    const int total = G * TO * 8;
    for (int i = tid * 4; i < total; i += NTHR * 4) {
      float4 v = *(const float4*)&sm[OFF_OUT + i];
      *(float4*)&outp[(size_t)blockIdx.x * total + i] = v;
    }
  }
}

}  // namespace

extern "C" void kernel_launch(void* const* d_in, const int* in_sizes, int n_in,
                              void* d_out, int out_size, void* d_ws, size_t ws_size,
                              hipStream_t stream) {
  (void)in_sizes; (void)n_in; (void)out_size; (void)ws_size;
  const float* inputs   = (const float*)d_in[0];
  const float* Wx       = (const float*)d_in[1];
  const float* Wh       = (const float*)d_in[2];
  const float* b_lstm   = (const float*)d_in[3];
  const float* W_params = (const float*)d_in[4];
  const float* b_params = (const float*)d_in[5];
  const float* W_out    = (const float*)d_in[6];
  const float* b_out    = (const float*)d_in[7];
  const int*   seqp     = (const int*)d_in[8];
  float* out = (float*)d_out;
  unsigned short* wsu = (unsigned short*)d_ws;

  constexpr int SETUP_N = WS_BIG_SLOTS + WS_SM_SLOTS;  // 9792
  setup_kernel<<<(SETUP_N + 255) / 256, 256, 0, stream>>>(wsu, Wx, Wh, W_params,
                                                          W_out);

  hipFuncSetAttribute((const void*)ntm_kernel,
                      hipFuncAttributeMaxDynamicSharedMemorySize, SMEM_BYTES);
  ntm_kernel<<<B_TOT / G, NTHR, SMEM_BYTES, stream>>>(
      inputs, wsu, b_lstm, b_params, b_out, W_out, seqp, out);
}